// Round 3
// baseline (722.652 us; speedup 1.0000x reference)
//
#include <hip/hip_runtime.h>

constexpr int B = 2, C = 64, H = 192, W = 192;
constexpr int HW = H * W;
constexpr int P = B * H * W;          // 73728 pixels
constexpr float EPS = 1e-5f;

// XCD-aware bijective block swizzle (all grids here are divisible by 8).
// Consecutive hardware bids round-robin across the 8 XCDs; this gives XCD i
// the contiguous work chunk [i*nwg/8, (i+1)*nwg/8). Chunks of ALL kernels
// cover the same 9216-pixel (48-row) image regions -> cross-kernel L2 reuse.
__device__ __forceinline__ int swz(int bid, int nwg) {
  return (bid & 7) * (nwg >> 3) + (bid >> 3);
}

// ---------------------------------------------------------------------------
// Kernel 1: NCHW -> NHWC transpose of x (64x64 LDS tile per (b,h,w-tile))
// ---------------------------------------------------------------------------
__global__ __launch_bounds__(256) void k_transpose(const float* __restrict__ x,
                                                   float* __restrict__ xt) {
  int blk = swz(blockIdx.x, B * H * (W / 64));
  int wt  = blk % (W / 64);
  int h   = (blk / (W / 64)) % H;
  int b   = blk / ((W / 64) * H);
  int w0  = wt * 64;
  __shared__ float tile[64][65];
  int tx = threadIdx.x & 63;
  int ty = threadIdx.x >> 6;
  #pragma unroll
  for (int c = ty; c < 64; c += 4)
    tile[c][tx] = x[((b * C + c) * H + h) * W + w0 + tx];
  __syncthreads();
  #pragma unroll
  for (int wi = ty; wi < 64; wi += 4)
    xt[((b * H + h) * W + w0 + wi) * 64 + tx] = tile[tx][wi];
}

// ---------------------------------------------------------------------------
// Kernel 2: off_sum = bn1(dw1x15) + bn2(dw15x1) + bn3(dw3x3)   (NHWC in/out)
// one wave per 4 consecutive-w pixels, lane = channel.
// ---------------------------------------------------------------------------
__global__ __launch_bounds__(256) void k_offsum(const float* __restrict__ xt,
    const float* __restrict__ w1, const float* __restrict__ b1, const float* __restrict__ bn1,
    const float* __restrict__ w2, const float* __restrict__ b2, const float* __restrict__ bn2,
    const float* __restrict__ w3, const float* __restrict__ b3, const float* __restrict__ bn3,
    float* __restrict__ out) {
  int wave = (swz(blockIdx.x, P / 16) * 256 + (int)threadIdx.x) >> 6;  // P/4 waves
  int c = threadIdx.x & 63;
  int w0 = (wave % (W / 4)) * 4;
  int h  = (wave / (W / 4)) % H;
  int b  = wave / ((W / 4) * H);
  const float* xb = xt + (size_t)b * HW * 64 + c;

  float s1[4] = {0.f, 0.f, 0.f, 0.f};
  float s2[4] = {0.f, 0.f, 0.f, 0.f};
  float s3[4] = {0.f, 0.f, 0.f, 0.f};

  // horizontal 1x15, pad 7: shared window w0-7 .. w0+10 (18 taps)
  {
    float xv[18];
    #pragma unroll
    for (int j = 0; j < 18; ++j) {
      int ww = w0 - 7 + j;
      xv[j] = (ww >= 0 && ww < W) ? xb[(h * W + ww) * 64] : 0.f;
    }
    #pragma unroll
    for (int j = 0; j < 15; ++j) {
      float wj = w1[c * 15 + j];
      #pragma unroll
      for (int p = 0; p < 4; ++p) s1[p] = fmaf(xv[p + j], wj, s1[p]);
    }
  }
  // vertical 15x1, pad 7
  #pragma unroll
  for (int j = 0; j < 15; ++j) {
    int hh = h - 7 + j;
    if (hh >= 0 && hh < H) {
      float wj = w2[c * 15 + j];
      #pragma unroll
      for (int p = 0; p < 4; ++p)
        s2[p] = fmaf(xb[(hh * W + w0 + p) * 64], wj, s2[p]);
    }
  }
  // 3x3, pad 1: per row shared window w0-1 .. w0+4 (6 values)
  #pragma unroll
  for (int dy = -1; dy <= 1; ++dy) {
    int hh = h + dy;
    if (hh < 0 || hh >= H) continue;
    float rv[6];
    #pragma unroll
    for (int j = 0; j < 6; ++j) {
      int ww = w0 - 1 + j;
      rv[j] = (ww >= 0 && ww < W) ? xb[(hh * W + ww) * 64] : 0.f;
    }
    #pragma unroll
    for (int dx = 0; dx < 3; ++dx) {
      float wj = w3[c * 9 + (dy + 1) * 3 + dx];
      #pragma unroll
      for (int p = 0; p < 4; ++p) s3[p] = fmaf(rv[p + dx], wj, s3[p]);
    }
  }

  float sc1 = bn1[c] / sqrtf(bn1[192 + c] + EPS);
  float sh1 = bn1[64 + c] - bn1[128 + c] * sc1;
  float sc2 = bn2[c] / sqrtf(bn2[192 + c] + EPS);
  float sh2 = bn2[64 + c] - bn2[128 + c] * sc2;
  float sc3 = bn3[c] / sqrtf(bn3[192 + c] + EPS);
  float sh3 = bn3[64 + c] - bn3[128 + c] * sc3;
  float bb1 = b1[c], bb2 = b2[c], bb3 = b3[c];
  #pragma unroll
  for (int p = 0; p < 4; ++p)
    out[((size_t)wave * 4 + p) * 64 + c] =
        fmaf(s1[p] + bb1, sc1, sh1) + fmaf(s2[p] + bb2, sc2, sh2) +
        fmaf(s3[p] + bb3, sc3, sh3);
}

// ---------------------------------------------------------------------------
// Kernel 3: offsets = bn(1x1 conv 64->18)   (NHWC: out[pix*18 + o])
// ---------------------------------------------------------------------------
__global__ __launch_bounds__(256) void k_offsets(const float* __restrict__ off_sum,
    const float* __restrict__ wq, const float* __restrict__ bq,
    const float* __restrict__ bnq, float* __restrict__ out) {
  int idx = swz(blockIdx.x, (P * 18) / 256) * 256 + (int)threadIdx.x;
  int o   = idx % 18;
  int pix = idx / 18;
  const float4* v  = (const float4*)(off_sum + (size_t)pix * 64);
  const float4* wv = (const float4*)(wq + o * 64);
  float s = 0.f;
  #pragma unroll
  for (int j = 0; j < 16; ++j) {
    float4 a = v[j], ww = wv[j];
    s = fmaf(a.x, ww.x, s); s = fmaf(a.y, ww.y, s);
    s = fmaf(a.z, ww.z, s); s = fmaf(a.w, ww.w, s);
  }
  float sc = bnq[o] / sqrtf(bnq[54 + o] + EPS);
  float sh = bnq[18 + o] - bnq[36 + o] * sc;
  out[idx] = fmaf(s + bq[o], sc, sh);
}

// ---------------------------------------------------------------------------
// Kernel 4: deform_sum over dilations {1,2,4}; one wave per 2 consecutive-w
// pixels, lane = channel. Coords wave-uniform; gathers are 256B coalesced.
// Bilinear fractions/corner-weights are shared across the 3 dilations
// (ky*d is an integer, so frac() is identical up to 1 ulp); d=2,4 corners
// derived by integer shifts. Center tap (ky=kx=0) fully CSEs across d.
// ---------------------------------------------------------------------------
__global__ __launch_bounds__(256) void k_deform(const float* __restrict__ xt,
                                                const float* __restrict__ offs,
                                                const float* __restrict__ wdef,
                                                float* __restrict__ dsum) {
  int wave = (swz(blockIdx.x, P / 8) * 256 + (int)threadIdx.x) >> 6;  // P/2 waves
  int c = threadIdx.x & 63;
  int w0 = (wave % (W / 2)) * 2;
  int h  = (wave / (W / 2)) % H;
  int b  = wave / ((W / 2) * H);
  const float* xb = xt + (size_t)b * HW * 64 + c;
  int pix0 = wave * 2;

  float offr[2][18];
  #pragma unroll
  for (int p = 0; p < 2; ++p) {
    const float* op = offs + (size_t)(pix0 + p) * 18;
    #pragma unroll
    for (int i = 0; i < 18; ++i) offr[p][i] = op[i];
  }
  float wd[27];
  #pragma unroll
  for (int i = 0; i < 3; ++i)
    #pragma unroll
    for (int k = 0; k < 9; ++k)
      wd[i * 9 + k] = wdef[i * C * 9 + c * 9 + k];

  float acc[2] = {0.f, 0.f};
  #pragma unroll
  for (int k = 0; k < 9; ++k) {
    const int ky = k / 3 - 1, kx = k % 3 - 1;
    #pragma unroll
    for (int p = 0; p < 2; ++p) {
      // d=1 coordinate, in exact reference rounding order: (off + h) + ky
      float ty = offr[p][2 * k]     + (float)h;
      float tx = offr[p][2 * k + 1] + (float)(w0 + p);
      float by = ty + (float)ky;
      float bx = tx + (float)kx;
      float y0f = floorf(by), x0f = floorf(bx);
      float wy1 = by - y0f, wx1 = bx - x0f;
      float wy0 = 1.f - wy1, wx0 = 1.f - wx1;
      float w00 = wy0 * wx0, w01 = wy0 * wx1;
      float w10 = wy1 * wx0, w11 = wy1 * wx1;
      int y0b = (int)y0f, x0b = (int)x0f;
      #pragma unroll
      for (int di = 0; di < 3; ++di) {
        const int d = (di == 0) ? 1 : (di == 1) ? 2 : 4;
        int y0 = y0b + ky * (d - 1), x0 = x0b + kx * (d - 1);
        int y1 = y0 + 1, x1 = x0 + 1;
        bool vy0 = (y0 >= 0) & (y0 < H);
        bool vy1 = (y1 >= 0) & (y1 < H);
        bool vx0 = (x0 >= 0) & (x0 < W);
        bool vx1 = (x1 >= 0) & (x1 < W);
        int y0c = min(max(y0, 0), H - 1), y1c = min(max(y1, 0), H - 1);
        int x0c = min(max(x0, 0), W - 1), x1c = min(max(x1, 0), W - 1);
        float v00 = (vy0 && vx0) ? xb[(y0c * W + x0c) * 64] : 0.f;
        float v01 = (vy0 && vx1) ? xb[(y0c * W + x1c) * 64] : 0.f;
        float v10 = (vy1 && vx0) ? xb[(y1c * W + x0c) * 64] : 0.f;
        float v11 = (vy1 && vx1) ? xb[(y1c * W + x1c) * 64] : 0.f;
        float bil = v00 * w00 + v01 * w01 + v10 * w10 + v11 * w11;
        acc[p] = fmaf(wd[di * 9 + k], bil, acc[p]);
      }
    }
  }
  #pragma unroll
  for (int p = 0; p < 2; ++p)
    dsum[(size_t)(pix0 + p) * 64 + c] = acc[p];
}

// ---------------------------------------------------------------------------
// Kernel 5: out = bn(1x1 conv 64->64) * x    (NHWC in, NCHW out)
// ---------------------------------------------------------------------------
__global__ __launch_bounds__(256) void k_final(const float* __restrict__ ds,
    const float* __restrict__ x, const float* __restrict__ wb,
    const float* __restrict__ bb, const float* __restrict__ bnb,
    float* __restrict__ out) {
  int blk = swz(blockIdx.x, P / 64);
  int w0 = (blk % (W / 64)) * 64;
  int h  = (blk / (W / 64)) % H;
  int b  = blk / ((W / 64) * H);
  __shared__ float dtile[64][65];       // [pixel][channel]
  __shared__ float wtile[64][64];       // [oc][ic]
  int tx = threadIdx.x & 63;
  int ty = threadIdx.x >> 6;
  int pixbase = (b * H + h) * W + w0;
  #pragma unroll
  for (int wi = ty; wi < 64; wi += 4)
    dtile[wi][tx] = ds[(size_t)(pixbase + wi) * 64 + tx];
  #pragma unroll
  for (int oc = ty; oc < 64; oc += 4)
    wtile[oc][tx] = wb[oc * 64 + tx];
  __syncthreads();
  #pragma unroll
  for (int j = 0; j < 16; ++j) {
    int oc = ty + 4 * j;                // wave-uniform
    float s = 0.f;
    #pragma unroll
    for (int k2 = 0; k2 < 64; ++k2)
      s = fmaf(dtile[tx][k2], wtile[oc][k2], s);
    float sc = bnb[oc] / sqrtf(bnb[192 + oc] + EPS);
    float sh = bnb[64 + oc] - bnb[128 + oc] * sc;
    float val = fmaf(s + bb[oc], sc, sh);
    int xi = ((b * C + oc) * H + h) * W + w0 + tx;
    out[xi] = val * x[xi];
  }
}

// ---------------------------------------------------------------------------
extern "C" void kernel_launch(void* const* d_in, const int* in_sizes, int n_in,
                              void* d_out, int out_size, void* d_ws, size_t ws_size,
                              hipStream_t stream) {
  const float* x     = (const float*)d_in[0];
  const float* w1    = (const float*)d_in[1];
  const float* b1    = (const float*)d_in[2];
  const float* bn1   = (const float*)d_in[3];
  const float* w2    = (const float*)d_in[4];
  const float* b2    = (const float*)d_in[5];
  const float* bn2   = (const float*)d_in[6];
  const float* w3    = (const float*)d_in[7];
  const float* b3    = (const float*)d_in[8];
  const float* bn3   = (const float*)d_in[9];
  const float* wbo   = (const float*)d_in[10];
  const float* bbo   = (const float*)d_in[11];
  const float* bnbo  = (const float*)d_in[12];
  const float* wdef  = (const float*)d_in[13];
  const float* wbal  = (const float*)d_in[14];
  const float* bbal  = (const float*)d_in[15];
  const float* bnbal = (const float*)d_in[16];
  float* out = (float*)d_out;

  float* xt      = (float*)d_ws;                 // P*64 floats (NHWC x)
  float* off_sum = xt + (size_t)P * 64;          // P*64 floats
  float* offs    = off_sum + (size_t)P * 64;     // P*18 floats
  float* dsum    = off_sum;                      // reuse off_sum after k_offsets

  k_transpose<<<B * H * (W / 64), 256, 0, stream>>>(x, xt);
  k_offsum<<<P / 16, 256, 0, stream>>>(xt, w1, b1, bn1, w2, b2, bn2, w3, b3, bn3, off_sum);
  k_offsets<<<(P * 18) / 256, 256, 0, stream>>>(off_sum, wbo, bbo, bnbo, offs);
  k_deform<<<P / 8, 256, 0, stream>>>(xt, offs, wdef, dsum);
  k_final<<<P / 64, 256, 0, stream>>>(dsum, x, wbal, bbal, bnbal, out);
}

// Round 4
// 487.590 us; speedup vs baseline: 1.4821x; 1.4821x over previous
//
#include <hip/hip_runtime.h>
#include <stdint.h>

constexpr int B = 2, C = 64, H = 192, W = 192;
constexpr int HW = H * W;
constexpr int P = B * H * W;          // 73728 pixels
constexpr float EPS = 1e-5f;

// XCD-aware bijective block swizzle (all grids divisible by 8). Chunks of ALL
// kernels cover the same contiguous pixel regions -> cross-kernel L2 reuse.
__device__ __forceinline__ int swz(int bid, int nwg) {
  return (bid & 7) * (nwg >> 3) + (bid >> 3);
}

// ---------------------------------------------------------------------------
// Kernel 1: NCHW -> NHWC transpose of x
// ---------------------------------------------------------------------------
__global__ __launch_bounds__(256) void k_transpose(const float* __restrict__ x,
                                                   float* __restrict__ xt) {
  int blk = swz(blockIdx.x, B * H * (W / 64));
  int wt  = blk % (W / 64);
  int h   = (blk / (W / 64)) % H;
  int b   = blk / ((W / 64) * H);
  int w0  = wt * 64;
  __shared__ float tile[64][65];
  int tx = threadIdx.x & 63;
  int ty = threadIdx.x >> 6;
  #pragma unroll
  for (int c = ty; c < 64; c += 4)
    tile[c][tx] = x[((b * C + c) * H + h) * W + w0 + tx];
  __syncthreads();
  #pragma unroll
  for (int wi = ty; wi < 64; wi += 4)
    xt[((b * H + h) * W + w0 + wi) * 64 + tx] = tile[tx][wi];
}

// ---------------------------------------------------------------------------
// Kernel 2: off_sum = bn1(dw1x15) + bn2(dw15x1) + bn3(dw3x3)   (NHWC in/out)
// ---------------------------------------------------------------------------
__global__ __launch_bounds__(256) void k_offsum(const float* __restrict__ xt,
    const float* __restrict__ w1, const float* __restrict__ b1, const float* __restrict__ bn1,
    const float* __restrict__ w2, const float* __restrict__ b2, const float* __restrict__ bn2,
    const float* __restrict__ w3, const float* __restrict__ b3, const float* __restrict__ bn3,
    float* __restrict__ out) {
  int wave = (swz(blockIdx.x, P / 16) * 256 + (int)threadIdx.x) >> 6;  // P/4 waves
  int c = threadIdx.x & 63;
  int w0 = (wave % (W / 4)) * 4;
  int h  = (wave / (W / 4)) % H;
  int b  = wave / ((W / 4) * H);
  const float* xb = xt + (size_t)b * HW * 64 + c;

  float s1[4] = {0.f, 0.f, 0.f, 0.f};
  float s2[4] = {0.f, 0.f, 0.f, 0.f};
  float s3[4] = {0.f, 0.f, 0.f, 0.f};

  {
    float xv[18];
    #pragma unroll
    for (int j = 0; j < 18; ++j) {
      int ww = w0 - 7 + j;
      xv[j] = (ww >= 0 && ww < W) ? xb[(h * W + ww) * 64] : 0.f;
    }
    #pragma unroll
    for (int j = 0; j < 15; ++j) {
      float wj = w1[c * 15 + j];
      #pragma unroll
      for (int p = 0; p < 4; ++p) s1[p] = fmaf(xv[p + j], wj, s1[p]);
    }
  }
  #pragma unroll
  for (int j = 0; j < 15; ++j) {
    int hh = h - 7 + j;
    if (hh >= 0 && hh < H) {
      float wj = w2[c * 15 + j];
      #pragma unroll
      for (int p = 0; p < 4; ++p)
        s2[p] = fmaf(xb[(hh * W + w0 + p) * 64], wj, s2[p]);
    }
  }
  #pragma unroll
  for (int dy = -1; dy <= 1; ++dy) {
    int hh = h + dy;
    if (hh < 0 || hh >= H) continue;
    float rv[6];
    #pragma unroll
    for (int j = 0; j < 6; ++j) {
      int ww = w0 - 1 + j;
      rv[j] = (ww >= 0 && ww < W) ? xb[(hh * W + ww) * 64] : 0.f;
    }
    #pragma unroll
    for (int dx = 0; dx < 3; ++dx) {
      float wj = w3[c * 9 + (dy + 1) * 3 + dx];
      #pragma unroll
      for (int p = 0; p < 4; ++p) s3[p] = fmaf(rv[p + dx], wj, s3[p]);
    }
  }

  float sc1 = bn1[c] / sqrtf(bn1[192 + c] + EPS);
  float sh1 = bn1[64 + c] - bn1[128 + c] * sc1;
  float sc2 = bn2[c] / sqrtf(bn2[192 + c] + EPS);
  float sh2 = bn2[64 + c] - bn2[128 + c] * sc2;
  float sc3 = bn3[c] / sqrtf(bn3[192 + c] + EPS);
  float sh3 = bn3[64 + c] - bn3[128 + c] * sc3;
  float bb1 = b1[c], bb2 = b2[c], bb3 = b3[c];
  #pragma unroll
  for (int p = 0; p < 4; ++p)
    out[((size_t)wave * 4 + p) * 64 + c] =
        fmaf(s1[p] + bb1, sc1, sh1) + fmaf(s2[p] + bb2, sc2, sh2) +
        fmaf(s3[p] + bb3, sc3, sh3);
}

// ---------------------------------------------------------------------------
// Kernel 3: offsets = bn(1x1 conv 64->18)   (NHWC: out[pix*18 + o])
// ---------------------------------------------------------------------------
__global__ __launch_bounds__(256) void k_offsets(const float* __restrict__ off_sum,
    const float* __restrict__ wq, const float* __restrict__ bq,
    const float* __restrict__ bnq, float* __restrict__ out) {
  int idx = swz(blockIdx.x, (P * 18) / 256) * 256 + (int)threadIdx.x;
  int o   = idx % 18;
  int pix = idx / 18;
  const float4* v  = (const float4*)(off_sum + (size_t)pix * 64);
  const float4* wv = (const float4*)(wq + o * 64);
  float s = 0.f;
  #pragma unroll
  for (int j = 0; j < 16; ++j) {
    float4 a = v[j], ww = wv[j];
    s = fmaf(a.x, ww.x, s); s = fmaf(a.y, ww.y, s);
    s = fmaf(a.z, ww.z, s); s = fmaf(a.w, ww.w, s);
  }
  float sc = bnq[o] / sqrtf(bnq[54 + o] + EPS);
  float sh = bnq[18 + o] - bnq[36 + o] * sc;
  out[idx] = fmaf(s + bq[o], sc, sh);
}

// ---------------------------------------------------------------------------
// Kernel 3b: precompute per (pixel, dil, tap): packed clamped corner coords
// (4 x u8, H=W=192<256) + 4 validity-folded bilinear weights (f32).
// One wave per pixel; lanes 0..26 = (dil*9 + tap). Exact per-dilation floors,
// validity folded separably: w_ij = (wyi*myi)*(wxj*mxj) == wyi*wxj*m_ij.
// ---------------------------------------------------------------------------
__global__ __launch_bounds__(256) void k_precomp(const float* __restrict__ offs,
                                                 uint32_t* __restrict__ pre) {
  int wave = (swz(blockIdx.x, P / 4) * 256 + (int)threadIdx.x) >> 6;  // P waves
  int lane = threadIdx.x & 63;
  if (lane >= 27) return;
  int di = lane / 9, k = lane % 9;
  int d  = 1 << di;                       // 1,2,4
  int w = wave % W, h = (wave / W) % H;
  float offy = offs[(size_t)wave * 18 + 2 * k];
  float offx = offs[(size_t)wave * 18 + 2 * k + 1];
  int ky = k / 3 - 1, kx = k % 3 - 1;
  // reference order: (off + coord) + ky*dil
  float yy = (offy + (float)h) + (float)(ky * d);
  float xx = (offx + (float)w) + (float)(kx * d);
  float y0f = floorf(yy), x0f = floorf(xx);
  float wy1 = yy - y0f, wx1 = xx - x0f;
  float wy0 = 1.f - wy1, wx0 = 1.f - wx1;
  // guard int-cast against extreme offsets
  int y0 = (int)fmaxf(fminf(y0f, 1.0e4f), -1.0e4f);
  int x0 = (int)fmaxf(fminf(x0f, 1.0e4f), -1.0e4f);
  int y1 = y0 + 1, x1 = x0 + 1;
  float my0 = (y0 >= 0 && y0 < H) ? 1.f : 0.f;
  float my1 = (y1 >= 0 && y1 < H) ? 1.f : 0.f;
  float mx0 = (x0 >= 0 && x0 < W) ? 1.f : 0.f;
  float mx1 = (x1 >= 0 && x1 < W) ? 1.f : 0.f;
  int y0c = min(max(y0, 0), H - 1), y1c = min(max(y1, 0), H - 1);
  int x0c = min(max(x0, 0), W - 1), x1c = min(max(x1, 0), W - 1);
  uint32_t packed = (uint32_t)y0c | ((uint32_t)y1c << 8) |
                    ((uint32_t)x0c << 16) | ((uint32_t)x1c << 24);
  float wy0m = wy0 * my0, wy1m = wy1 * my1;
  float wx0m = wx0 * mx0, wx1m = wx1 * mx1;
  uint32_t* pp = pre + (size_t)wave * 135 + lane * 5;
  pp[0] = packed;
  pp[1] = __float_as_uint(wy0m * wx0m);   // == wy0*wx0 when valid, 0 otherwise
  pp[2] = __float_as_uint(wy0m * wx1m);
  pp[3] = __float_as_uint(wy1m * wx0m);
  pp[4] = __float_as_uint(wy1m * wx1m);
}

// ---------------------------------------------------------------------------
// Kernel 4: deform_sum. One wave per pixel, lane = channel. All coordinate
// math precomputed; per tap: 5 uniform (scalar) dwords + 4 coalesced gathers
// + 5 FMAs. Minimal VGPR state -> high occupancy (was the r3 bottleneck:
// VGPR=164, occupancy 11.8%).
// ---------------------------------------------------------------------------
__global__ __launch_bounds__(256) void k_deform(const float* __restrict__ xt,
                                                const uint32_t* __restrict__ pre,
                                                const float* __restrict__ wdef,
                                                float* __restrict__ dsum) {
  int wave = (swz(blockIdx.x, P / 4) * 256 + (int)threadIdx.x) >> 6;  // P waves
  int c = threadIdx.x & 63;
  int spix = __builtin_amdgcn_readfirstlane(wave);
  int b = spix / HW;
  const float* xb = xt + (size_t)b * HW * 64 + c;
  const uint32_t* pp = pre + (size_t)spix * 135;
  const float* wdc = wdef + c * 9;
  float acc = 0.f;
  #pragma unroll
  for (int di = 0; di < 3; ++di) {
    #pragma unroll
    for (int k = 0; k < 9; ++k) {
      const uint32_t* ps = pp + (di * 9 + k) * 5;
      uint32_t pk = ps[0];
      float w00 = __uint_as_float(ps[1]);
      float w01 = __uint_as_float(ps[2]);
      float w10 = __uint_as_float(ps[3]);
      float w11 = __uint_as_float(ps[4]);
      int y0 = pk & 255, y1 = (pk >> 8) & 255;
      int x0 = (pk >> 16) & 255, x1 = pk >> 24;
      int r0 = y0 * W, r1 = y1 * W;
      float v00 = xb[(size_t)(r0 + x0) * 64];
      float v01 = xb[(size_t)(r0 + x1) * 64];
      float v10 = xb[(size_t)(r1 + x0) * 64];
      float v11 = xb[(size_t)(r1 + x1) * 64];
      float bil = fmaf(v11, w11, fmaf(v10, w10, fmaf(v01, w01, v00 * w00)));
      acc = fmaf(wdc[di * C * 9 + k], bil, acc);
    }
  }
  dsum[(size_t)wave * 64 + c] = acc;
}

// ---------------------------------------------------------------------------
// Kernel 5: out = bn(1x1 conv 64->64) * x    (NHWC in, NCHW out)
// ---------------------------------------------------------------------------
__global__ __launch_bounds__(256) void k_final(const float* __restrict__ ds,
    const float* __restrict__ x, const float* __restrict__ wb,
    const float* __restrict__ bb, const float* __restrict__ bnb,
    float* __restrict__ out) {
  int blk = swz(blockIdx.x, P / 64);
  int w0 = (blk % (W / 64)) * 64;
  int h  = (blk / (W / 64)) % H;
  int b  = blk / ((W / 64) * H);
  __shared__ float dtile[64][65];       // [pixel][channel]
  __shared__ float wtile[64][64];       // [oc][ic]
  int tx = threadIdx.x & 63;
  int ty = threadIdx.x >> 6;
  int pixbase = (b * H + h) * W + w0;
  #pragma unroll
  for (int wi = ty; wi < 64; wi += 4)
    dtile[wi][tx] = ds[(size_t)(pixbase + wi) * 64 + tx];
  #pragma unroll
  for (int oc = ty; oc < 64; oc += 4)
    wtile[oc][tx] = wb[oc * 64 + tx];
  __syncthreads();
  #pragma unroll
  for (int j = 0; j < 16; ++j) {
    int oc = ty + 4 * j;                // wave-uniform
    float s = 0.f;
    #pragma unroll
    for (int k2 = 0; k2 < 64; ++k2)
      s = fmaf(dtile[tx][k2], wtile[oc][k2], s);
    float sc = bnb[oc] / sqrtf(bnb[192 + oc] + EPS);
    float sh = bnb[64 + oc] - bnb[128 + oc] * sc;
    float val = fmaf(s + bb[oc], sc, sh);
    int xi = ((b * C + oc) * H + h) * W + w0 + tx;
    out[xi] = val * x[xi];
  }
}

// ---------------------------------------------------------------------------
extern "C" void kernel_launch(void* const* d_in, const int* in_sizes, int n_in,
                              void* d_out, int out_size, void* d_ws, size_t ws_size,
                              hipStream_t stream) {
  const float* x     = (const float*)d_in[0];
  const float* w1    = (const float*)d_in[1];
  const float* b1    = (const float*)d_in[2];
  const float* bn1   = (const float*)d_in[3];
  const float* w2    = (const float*)d_in[4];
  const float* b2    = (const float*)d_in[5];
  const float* bn2   = (const float*)d_in[6];
  const float* w3    = (const float*)d_in[7];
  const float* b3    = (const float*)d_in[8];
  const float* bn3   = (const float*)d_in[9];
  const float* wbo   = (const float*)d_in[10];
  const float* bbo   = (const float*)d_in[11];
  const float* bnbo  = (const float*)d_in[12];
  const float* wdef  = (const float*)d_in[13];
  const float* wbal  = (const float*)d_in[14];
  const float* bbal  = (const float*)d_in[15];
  const float* bnbal = (const float*)d_in[16];
  float* out = (float*)d_out;

  float*    xt      = (float*)d_ws;                      // P*64 f
  float*    off_sum = xt + (size_t)P * 64;               // P*64 f
  float*    offs    = off_sum + (size_t)P * 64;          // P*18 f
  uint32_t* pre     = (uint32_t*)(offs + (size_t)P * 18);// P*135 u32 (39.8 MB)
  float*    dsum    = off_sum;                           // reuse after k_offsets

  k_transpose<<<B * H * (W / 64), 256, 0, stream>>>(x, xt);
  k_offsum<<<P / 16, 256, 0, stream>>>(xt, w1, b1, bn1, w2, b2, bn2, w3, b3, bn3, off_sum);
  k_offsets<<<(P * 18) / 256, 256, 0, stream>>>(off_sum, wbo, bbo, bnbo, offs);
  k_precomp<<<P / 4, 256, 0, stream>>>(offs, pre);
  k_deform<<<P / 4, 256, 0, stream>>>(xt, pre, wdef, dsum);
  k_final<<<P / 64, 256, 0, stream>>>(dsum, x, wbal, bbal, bnbal, out);
}

// Round 5
// 304.678 us; speedup vs baseline: 2.3719x; 1.6003x over previous
//
#include <hip/hip_runtime.h>
#include <stdint.h>

constexpr int B = 2, C = 64, H = 192, W = 192;
constexpr int HW = H * W;
constexpr int P = B * H * W;          // 73728 pixels
constexpr float EPS = 1e-5f;

// XCD-aware bijective block swizzle (all grids divisible by 8). Chunks of ALL
// kernels cover the same contiguous pixel regions -> cross-kernel L2 reuse.
__device__ __forceinline__ int swz(int bid, int nwg) {
  return (bid & 7) * (nwg >> 3) + (bid >> 3);
}

// ---------------------------------------------------------------------------
// Kernel 1: NCHW -> NHWC transpose of x
// ---------------------------------------------------------------------------
__global__ __launch_bounds__(256) void k_transpose(const float* __restrict__ x,
                                                   float* __restrict__ xt) {
  int blk = swz(blockIdx.x, B * H * (W / 64));
  int wt  = blk % (W / 64);
  int h   = (blk / (W / 64)) % H;
  int b   = blk / ((W / 64) * H);
  int w0  = wt * 64;
  __shared__ float tile[64][65];
  int tx = threadIdx.x & 63;
  int ty = threadIdx.x >> 6;
  #pragma unroll
  for (int c = ty; c < 64; c += 4)
    tile[c][tx] = x[((b * C + c) * H + h) * W + w0 + tx];
  __syncthreads();
  #pragma unroll
  for (int wi = ty; wi < 64; wi += 4)
    xt[((b * H + h) * W + w0 + wi) * 64 + tx] = tile[tx][wi];
}

// ---------------------------------------------------------------------------
// Kernel 2: off_sum = bn1(dw1x15) + bn2(dw15x1) + bn3(dw3x3)   (NHWC in/out)
// ---------------------------------------------------------------------------
__global__ __launch_bounds__(256) void k_offsum(const float* __restrict__ xt,
    const float* __restrict__ w1, const float* __restrict__ b1, const float* __restrict__ bn1,
    const float* __restrict__ w2, const float* __restrict__ b2, const float* __restrict__ bn2,
    const float* __restrict__ w3, const float* __restrict__ b3, const float* __restrict__ bn3,
    float* __restrict__ out) {
  int wave = (swz(blockIdx.x, P / 16) * 256 + (int)threadIdx.x) >> 6;  // P/4 waves
  int c = threadIdx.x & 63;
  int w0 = (wave % (W / 4)) * 4;
  int h  = (wave / (W / 4)) % H;
  int b  = wave / ((W / 4) * H);
  const float* xb = xt + (size_t)b * HW * 64 + c;

  float s1[4] = {0.f, 0.f, 0.f, 0.f};
  float s2[4] = {0.f, 0.f, 0.f, 0.f};
  float s3[4] = {0.f, 0.f, 0.f, 0.f};

  {
    float xv[18];
    #pragma unroll
    for (int j = 0; j < 18; ++j) {
      int ww = w0 - 7 + j;
      xv[j] = (ww >= 0 && ww < W) ? xb[(h * W + ww) * 64] : 0.f;
    }
    #pragma unroll
    for (int j = 0; j < 15; ++j) {
      float wj = w1[c * 15 + j];
      #pragma unroll
      for (int p = 0; p < 4; ++p) s1[p] = fmaf(xv[p + j], wj, s1[p]);
    }
  }
  #pragma unroll
  for (int j = 0; j < 15; ++j) {
    int hh = h - 7 + j;
    if (hh >= 0 && hh < H) {
      float wj = w2[c * 15 + j];
      #pragma unroll
      for (int p = 0; p < 4; ++p)
        s2[p] = fmaf(xb[(hh * W + w0 + p) * 64], wj, s2[p]);
    }
  }
  #pragma unroll
  for (int dy = -1; dy <= 1; ++dy) {
    int hh = h + dy;
    if (hh < 0 || hh >= H) continue;
    float rv[6];
    #pragma unroll
    for (int j = 0; j < 6; ++j) {
      int ww = w0 - 1 + j;
      rv[j] = (ww >= 0 && ww < W) ? xb[(hh * W + ww) * 64] : 0.f;
    }
    #pragma unroll
    for (int dx = 0; dx < 3; ++dx) {
      float wj = w3[c * 9 + (dy + 1) * 3 + dx];
      #pragma unroll
      for (int p = 0; p < 4; ++p) s3[p] = fmaf(rv[p + dx], wj, s3[p]);
    }
  }

  float sc1 = bn1[c] / sqrtf(bn1[192 + c] + EPS);
  float sh1 = bn1[64 + c] - bn1[128 + c] * sc1;
  float sc2 = bn2[c] / sqrtf(bn2[192 + c] + EPS);
  float sh2 = bn2[64 + c] - bn2[128 + c] * sc2;
  float sc3 = bn3[c] / sqrtf(bn3[192 + c] + EPS);
  float sh3 = bn3[64 + c] - bn3[128 + c] * sc3;
  float bb1 = b1[c], bb2 = b2[c], bb3 = b3[c];
  #pragma unroll
  for (int p = 0; p < 4; ++p)
    out[((size_t)wave * 4 + p) * 64 + c] =
        fmaf(s1[p] + bb1, sc1, sh1) + fmaf(s2[p] + bb2, sc2, sh2) +
        fmaf(s3[p] + bb3, sc3, sh3);
}

// ---------------------------------------------------------------------------
// Kernel 3: offsets = bn(1x1 conv 64->18)   (NHWC: out[pix*18 + o])
// ---------------------------------------------------------------------------
__global__ __launch_bounds__(256) void k_offsets(const float* __restrict__ off_sum,
    const float* __restrict__ wq, const float* __restrict__ bq,
    const float* __restrict__ bnq, float* __restrict__ out) {
  int idx = swz(blockIdx.x, (P * 18) / 256) * 256 + (int)threadIdx.x;
  int o   = idx % 18;
  int pix = idx / 18;
  const float4* v  = (const float4*)(off_sum + (size_t)pix * 64);
  const float4* wv = (const float4*)(wq + o * 64);
  float s = 0.f;
  #pragma unroll
  for (int j = 0; j < 16; ++j) {
    float4 a = v[j], ww = wv[j];
    s = fmaf(a.x, ww.x, s); s = fmaf(a.y, ww.y, s);
    s = fmaf(a.z, ww.z, s); s = fmaf(a.w, ww.w, s);
  }
  float sc = bnq[o] / sqrtf(bnq[54 + o] + EPS);
  float sh = bnq[18 + o] - bnq[36 + o] * sc;
  out[idx] = fmaf(s + bq[o], sc, sh);
}

// ---------------------------------------------------------------------------
// Kernel 3b: precompute per (pixel, dil, tap): packed clamped corner coords
// (4 x u8) + 4 validity-folded bilinear weights (f32).
// ---------------------------------------------------------------------------
__global__ __launch_bounds__(256) void k_precomp(const float* __restrict__ offs,
                                                 uint32_t* __restrict__ pre) {
  int wave = (swz(blockIdx.x, P / 4) * 256 + (int)threadIdx.x) >> 6;  // P waves
  int lane = threadIdx.x & 63;
  if (lane >= 27) return;
  int di = lane / 9, k = lane % 9;
  int d  = 1 << di;                       // 1,2,4
  int w = wave % W, h = (wave / W) % H;
  float offy = offs[(size_t)wave * 18 + 2 * k];
  float offx = offs[(size_t)wave * 18 + 2 * k + 1];
  int ky = k / 3 - 1, kx = k % 3 - 1;
  float yy = (offy + (float)h) + (float)(ky * d);
  float xx = (offx + (float)w) + (float)(kx * d);
  float y0f = floorf(yy), x0f = floorf(xx);
  float wy1 = yy - y0f, wx1 = xx - x0f;
  float wy0 = 1.f - wy1, wx0 = 1.f - wx1;
  int y0 = (int)fmaxf(fminf(y0f, 1.0e4f), -1.0e4f);
  int x0 = (int)fmaxf(fminf(x0f, 1.0e4f), -1.0e4f);
  int y1 = y0 + 1, x1 = x0 + 1;
  float my0 = (y0 >= 0 && y0 < H) ? 1.f : 0.f;
  float my1 = (y1 >= 0 && y1 < H) ? 1.f : 0.f;
  float mx0 = (x0 >= 0 && x0 < W) ? 1.f : 0.f;
  float mx1 = (x1 >= 0 && x1 < W) ? 1.f : 0.f;
  int y0c = min(max(y0, 0), H - 1), y1c = min(max(y1, 0), H - 1);
  int x0c = min(max(x0, 0), W - 1), x1c = min(max(x1, 0), W - 1);
  uint32_t packed = (uint32_t)y0c | ((uint32_t)y1c << 8) |
                    ((uint32_t)x0c << 16) | ((uint32_t)x1c << 24);
  float wy0m = wy0 * my0, wy1m = wy1 * my1;
  float wx0m = wx0 * mx0, wx1m = wx1 * mx1;
  uint32_t* pp = pre + (size_t)wave * 135 + lane * 5;
  pp[0] = packed;
  pp[1] = __float_as_uint(wy0m * wx0m);
  pp[2] = __float_as_uint(wy0m * wx1m);
  pp[3] = __float_as_uint(wy1m * wx0m);
  pp[4] = __float_as_uint(wy1m * wx1m);
}

// ---------------------------------------------------------------------------
// Kernel 4: deform_sum. One wave per pixel, lane = channel.
// ---------------------------------------------------------------------------
__global__ __launch_bounds__(256) void k_deform(const float* __restrict__ xt,
                                                const uint32_t* __restrict__ pre,
                                                const float* __restrict__ wdef,
                                                float* __restrict__ dsum) {
  int wave = (swz(blockIdx.x, P / 4) * 256 + (int)threadIdx.x) >> 6;  // P waves
  int c = threadIdx.x & 63;
  int spix = __builtin_amdgcn_readfirstlane(wave);
  int b = spix / HW;
  const float* xb = xt + (size_t)b * HW * 64 + c;
  const uint32_t* pp = pre + (size_t)spix * 135;
  const float* wdc = wdef + c * 9;
  float acc = 0.f;
  #pragma unroll
  for (int di = 0; di < 3; ++di) {
    #pragma unroll
    for (int k = 0; k < 9; ++k) {
      const uint32_t* ps = pp + (di * 9 + k) * 5;
      uint32_t pk = ps[0];
      float w00 = __uint_as_float(ps[1]);
      float w01 = __uint_as_float(ps[2]);
      float w10 = __uint_as_float(ps[3]);
      float w11 = __uint_as_float(ps[4]);
      int y0 = pk & 255, y1 = (pk >> 8) & 255;
      int x0 = (pk >> 16) & 255, x1 = pk >> 24;
      int r0 = y0 * W, r1 = y1 * W;
      float v00 = xb[(size_t)(r0 + x0) * 64];
      float v01 = xb[(size_t)(r0 + x1) * 64];
      float v10 = xb[(size_t)(r1 + x0) * 64];
      float v11 = xb[(size_t)(r1 + x1) * 64];
      float bil = fmaf(v11, w11, fmaf(v10, w10, fmaf(v01, w01, v00 * w00)));
      acc = fmaf(wdc[di * C * 9 + k], bil, acc);
    }
  }
  dsum[(size_t)wave * 64 + c] = acc;
}

// ---------------------------------------------------------------------------
// Kernel 5: out = bn(1x1 conv 64->64) * x    (NHWC in, NCHW out)
// v2: pixel channel-vector in 64 VGPRs (16x ds_read_b128, stride-68 pad);
// weights via wave-uniform s_load (oc readfirstlane'd); 4 independent acc
// chains; BN scale/shift (+bias folded) precomputed to a 64-entry LDS table.
// Was 208 us: 2048 scalar ds_reads + 64-deep dependent FMA chain + 16 sqrtf
// per thread. Now 16 LDS vec-reads + 1024 FMA per wave.
// ---------------------------------------------------------------------------
__global__ __launch_bounds__(256) void k_final(const float* __restrict__ ds,
    const float* __restrict__ x, const float* __restrict__ wb,
    const float* __restrict__ bb, const float* __restrict__ bnb,
    float* __restrict__ out) {
  int blk = swz(blockIdx.x, P / 64);
  int w0 = (blk % (W / 64)) * 64;
  int h  = (blk / (W / 64)) % H;
  int b  = blk / ((W / 64) * H);
  __shared__ float dtile[64][68];       // [pixel][channel], padded for b128
  __shared__ float scs[64], shb[64];    // BN scale / (bias*sc + shift)
  int tx = threadIdx.x & 63;
  int ty = threadIdx.x >> 6;
  int pixbase = (b * H + h) * W + w0;

  // coalesced stage: 4 passes x 256 threads x float4 = 16 KB
  {
    int pr  = threadIdx.x >> 4;          // 0..15
    int ic4 = (threadIdx.x & 15) * 4;    // channel quad
    #pragma unroll
    for (int pass = 0; pass < 4; ++pass) {
      int pix = pass * 16 + pr;
      float4 v = *(const float4*)&ds[(size_t)(pixbase + pix) * 64 + ic4];
      *(float4*)&dtile[pix][ic4] = v;
    }
  }
  if (threadIdx.x < 64) {
    float g = bnb[threadIdx.x], vv = bnb[192 + threadIdx.x];
    float sc = g / sqrtf(vv + EPS);
    scs[threadIdx.x] = sc;
    shb[threadIdx.x] = fmaf(bb[threadIdx.x], sc,
                            bnb[64 + threadIdx.x] - bnb[128 + threadIdx.x] * sc);
  }
  __syncthreads();

  // pixel vector -> registers (b128, stride 68: aligned, 2-way aliasing only)
  float dreg[64];
  #pragma unroll
  for (int q = 0; q < 16; ++q) {
    float4 v = *(float4*)&dtile[tx][q * 4];
    dreg[4 * q + 0] = v.x; dreg[4 * q + 1] = v.y;
    dreg[4 * q + 2] = v.z; dreg[4 * q + 3] = v.w;
  }

  int ocb = __builtin_amdgcn_readfirstlane(ty);   // force SGPR weight loads
  #pragma unroll
  for (int j = 0; j < 16; ++j) {
    int oc = ocb + 4 * j;
    const float* wr = wb + oc * 64;
    float a0 = 0.f, a1 = 0.f, a2 = 0.f, a3 = 0.f;
    #pragma unroll
    for (int q = 0; q < 16; ++q) {
      a0 = fmaf(dreg[4 * q + 0], wr[4 * q + 0], a0);
      a1 = fmaf(dreg[4 * q + 1], wr[4 * q + 1], a1);
      a2 = fmaf(dreg[4 * q + 2], wr[4 * q + 2], a2);
      a3 = fmaf(dreg[4 * q + 3], wr[4 * q + 3], a3);
    }
    float s = (a0 + a1) + (a2 + a3);
    float val = fmaf(s, scs[oc], shb[oc]);
    int xi = ((b * C + oc) * H + h) * W + w0 + tx;
    out[xi] = val * x[xi];
  }
}

// ---------------------------------------------------------------------------
extern "C" void kernel_launch(void* const* d_in, const int* in_sizes, int n_in,
                              void* d_out, int out_size, void* d_ws, size_t ws_size,
                              hipStream_t stream) {
  const float* x     = (const float*)d_in[0];
  const float* w1    = (const float*)d_in[1];
  const float* b1    = (const float*)d_in[2];
  const float* bn1   = (const float*)d_in[3];
  const float* w2    = (const float*)d_in[4];
  const float* b2    = (const float*)d_in[5];
  const float* bn2   = (const float*)d_in[6];
  const float* w3    = (const float*)d_in[7];
  const float* b3    = (const float*)d_in[8];
  const float* bn3   = (const float*)d_in[9];
  const float* wbo   = (const float*)d_in[10];
  const float* bbo   = (const float*)d_in[11];
  const float* bnbo  = (const float*)d_in[12];
  const float* wdef  = (const float*)d_in[13];
  const float* wbal  = (const float*)d_in[14];
  const float* bbal  = (const float*)d_in[15];
  const float* bnbal = (const float*)d_in[16];
  float* out = (float*)d_out;

  float*    xt      = (float*)d_ws;                      // P*64 f
  float*    off_sum = xt + (size_t)P * 64;               // P*64 f
  float*    offs    = off_sum + (size_t)P * 64;          // P*18 f
  uint32_t* pre     = (uint32_t*)(offs + (size_t)P * 18);// P*135 u32 (39.8 MB)
  float*    dsum    = off_sum;                           // reuse after k_offsets

  k_transpose<<<B * H * (W / 64), 256, 0, stream>>>(x, xt);
  k_offsum<<<P / 16, 256, 0, stream>>>(xt, w1, b1, bn1, w2, b2, bn2, w3, b3, bn3, off_sum);
  k_offsets<<<(P * 18) / 256, 256, 0, stream>>>(off_sum, wbo, bbo, bnbo, offs);
  k_precomp<<<P / 4, 256, 0, stream>>>(offs, pre);
  k_deform<<<P / 4, 256, 0, stream>>>(xt, pre, wdef, dsum);
  k_final<<<P / 64, 256, 0, stream>>>(dsum, x, wbal, bbal, bnbal, out);
}

// Round 6
// 291.273 us; speedup vs baseline: 2.4810x; 1.0460x over previous
//
#include <hip/hip_runtime.h>
#include <stdint.h>

constexpr int B = 2, C = 64, H = 192, W = 192;
constexpr int HW = H * W;
constexpr int P = B * H * W;          // 73728 pixels
constexpr float EPS = 1e-5f;

// XCD-aware bijective block swizzle (all grids divisible by 8). Chunks of ALL
// kernels cover the same contiguous pixel regions -> cross-kernel L2 reuse.
__device__ __forceinline__ int swz(int bid, int nwg) {
  return (bid & 7) * (nwg >> 3) + (bid >> 3);
}

// ---------------------------------------------------------------------------
// Kernel 0: transpose weight tensors to channel-contiguous [tap][c] layouts.
// Runs once, ~4K elements. Fixes catastrophic per-lane stride-60B/36B weight
// loads in k_offsum/k_deform (each touched ~60/36 L1 lines per instruction).
// ---------------------------------------------------------------------------
__global__ __launch_bounds__(256) void k_prepw(const float* __restrict__ w1,
    const float* __restrict__ w2, const float* __restrict__ w3,
    const float* __restrict__ wdef, float* __restrict__ w1t,
    float* __restrict__ w2t, float* __restrict__ w3t, float* __restrict__ wdeft) {
  int t = threadIdx.x;
  for (int i = t; i < 960; i += 256) {        // [15][64]
    int c = i & 63, j = i >> 6;
    w1t[i] = w1[c * 15 + j];
    w2t[i] = w2[c * 15 + j];
  }
  for (int i = t; i < 576; i += 256) {        // [9][64]
    int c = i & 63, j = i >> 6;
    w3t[i] = w3[c * 9 + j];
  }
  for (int i = t; i < 1728; i += 256) {       // [27][64] (di*9+k major)
    int c = i & 63, jk = i >> 6;
    int di = jk / 9, k = jk % 9;
    wdeft[i] = wdef[di * (C * 9) + c * 9 + k];
  }
}

// ---------------------------------------------------------------------------
// Kernel 1: NCHW -> NHWC transpose of x
// ---------------------------------------------------------------------------
__global__ __launch_bounds__(256) void k_transpose(const float* __restrict__ x,
                                                   float* __restrict__ xt) {
  int blk = swz(blockIdx.x, B * H * (W / 64));
  int wt  = blk % (W / 64);
  int h   = (blk / (W / 64)) % H;
  int b   = blk / ((W / 64) * H);
  int w0  = wt * 64;
  __shared__ float tile[64][65];
  int tx = threadIdx.x & 63;
  int ty = threadIdx.x >> 6;
  #pragma unroll
  for (int c = ty; c < 64; c += 4)
    tile[c][tx] = x[((b * C + c) * H + h) * W + w0 + tx];
  __syncthreads();
  #pragma unroll
  for (int wi = ty; wi < 64; wi += 4)
    xt[((b * H + h) * W + w0 + wi) * 64 + tx] = tile[tx][wi];
}

// ---------------------------------------------------------------------------
// Kernel 2: off_sum = bn1(dw1x15) + bn2(dw15x1) + bn3(dw3x3)   (NHWC in/out)
// One wave per 4 consecutive-w pixels, lane = channel. Weights now coalesced.
// ---------------------------------------------------------------------------
__global__ __launch_bounds__(256) void k_offsum(const float* __restrict__ xt,
    const float* __restrict__ w1t, const float* __restrict__ b1, const float* __restrict__ bn1,
    const float* __restrict__ w2t, const float* __restrict__ b2, const float* __restrict__ bn2,
    const float* __restrict__ w3t, const float* __restrict__ b3, const float* __restrict__ bn3,
    float* __restrict__ out) {
  int wave = (swz(blockIdx.x, P / 16) * 256 + (int)threadIdx.x) >> 6;  // P/4 waves
  int c = threadIdx.x & 63;
  int w0 = (wave % (W / 4)) * 4;
  int h  = (wave / (W / 4)) % H;
  int b  = wave / ((W / 4) * H);
  const float* xb = xt + (size_t)b * HW * 64 + c;

  float s1[4] = {0.f, 0.f, 0.f, 0.f};
  float s2[4] = {0.f, 0.f, 0.f, 0.f};
  float s3[4] = {0.f, 0.f, 0.f, 0.f};

  {
    float xv[18];
    #pragma unroll
    for (int j = 0; j < 18; ++j) {
      int ww = w0 - 7 + j;
      xv[j] = (ww >= 0 && ww < W) ? xb[(h * W + ww) * 64] : 0.f;
    }
    #pragma unroll
    for (int j = 0; j < 15; ++j) {
      float wj = w1t[j * 64 + c];
      #pragma unroll
      for (int p = 0; p < 4; ++p) s1[p] = fmaf(xv[p + j], wj, s1[p]);
    }
  }
  #pragma unroll
  for (int j = 0; j < 15; ++j) {
    int hh = h - 7 + j;
    if (hh >= 0 && hh < H) {
      float wj = w2t[j * 64 + c];
      #pragma unroll
      for (int p = 0; p < 4; ++p)
        s2[p] = fmaf(xb[(hh * W + w0 + p) * 64], wj, s2[p]);
    }
  }
  #pragma unroll
  for (int dy = -1; dy <= 1; ++dy) {
    int hh = h + dy;
    if (hh < 0 || hh >= H) continue;
    float rv[6];
    #pragma unroll
    for (int j = 0; j < 6; ++j) {
      int ww = w0 - 1 + j;
      rv[j] = (ww >= 0 && ww < W) ? xb[(hh * W + ww) * 64] : 0.f;
    }
    #pragma unroll
    for (int dx = 0; dx < 3; ++dx) {
      float wj = w3t[((dy + 1) * 3 + dx) * 64 + c];
      #pragma unroll
      for (int p = 0; p < 4; ++p) s3[p] = fmaf(rv[p + dx], wj, s3[p]);
    }
  }

  float sc1 = bn1[c] / sqrtf(bn1[192 + c] + EPS);
  float sh1 = bn1[64 + c] - bn1[128 + c] * sc1;
  float sc2 = bn2[c] / sqrtf(bn2[192 + c] + EPS);
  float sh2 = bn2[64 + c] - bn2[128 + c] * sc2;
  float sc3 = bn3[c] / sqrtf(bn3[192 + c] + EPS);
  float sh3 = bn3[64 + c] - bn3[128 + c] * sc3;
  float bb1 = b1[c], bb2 = b2[c], bb3 = b3[c];
  #pragma unroll
  for (int p = 0; p < 4; ++p)
    out[((size_t)wave * 4 + p) * 64 + c] =
        fmaf(s1[p] + bb1, sc1, sh1) + fmaf(s2[p] + bb2, sc2, sh2) +
        fmaf(s3[p] + bb3, sc3, sh3);
}

// ---------------------------------------------------------------------------
// Kernel 3: offsets = bn(1x1 conv 64->18)   (NHWC: out[pix*18 + o])
// ---------------------------------------------------------------------------
__global__ __launch_bounds__(256) void k_offsets(const float* __restrict__ off_sum,
    const float* __restrict__ wq, const float* __restrict__ bq,
    const float* __restrict__ bnq, float* __restrict__ out) {
  int idx = swz(blockIdx.x, (P * 18) / 256) * 256 + (int)threadIdx.x;
  int o   = idx % 18;
  int pix = idx / 18;
  const float4* v  = (const float4*)(off_sum + (size_t)pix * 64);
  const float4* wv = (const float4*)(wq + o * 64);
  float s = 0.f;
  #pragma unroll
  for (int j = 0; j < 16; ++j) {
    float4 a = v[j], ww = wv[j];
    s = fmaf(a.x, ww.x, s); s = fmaf(a.y, ww.y, s);
    s = fmaf(a.z, ww.z, s); s = fmaf(a.w, ww.w, s);
  }
  float sc = bnq[o] / sqrtf(bnq[54 + o] + EPS);
  float sh = bnq[18 + o] - bnq[36 + o] * sc;
  out[idx] = fmaf(s + bq[o], sc, sh);
}

// ---------------------------------------------------------------------------
// Kernel 3b: precompute per (pixel, dil, tap): packed clamped corner coords
// (4 x u8) + 4 validity-folded bilinear weights (f32).
// ---------------------------------------------------------------------------
__global__ __launch_bounds__(256) void k_precomp(const float* __restrict__ offs,
                                                 uint32_t* __restrict__ pre) {
  int wave = (swz(blockIdx.x, P / 4) * 256 + (int)threadIdx.x) >> 6;  // P waves
  int lane = threadIdx.x & 63;
  if (lane >= 27) return;
  int di = lane / 9, k = lane % 9;
  int d  = 1 << di;                       // 1,2,4
  int w = wave % W, h = (wave / W) % H;
  float offy = offs[(size_t)wave * 18 + 2 * k];
  float offx = offs[(size_t)wave * 18 + 2 * k + 1];
  int ky = k / 3 - 1, kx = k % 3 - 1;
  float yy = (offy + (float)h) + (float)(ky * d);
  float xx = (offx + (float)w) + (float)(kx * d);
  float y0f = floorf(yy), x0f = floorf(xx);
  float wy1 = yy - y0f, wx1 = xx - x0f;
  float wy0 = 1.f - wy1, wx0 = 1.f - wx1;
  int y0 = (int)fmaxf(fminf(y0f, 1.0e4f), -1.0e4f);
  int x0 = (int)fmaxf(fminf(x0f, 1.0e4f), -1.0e4f);
  int y1 = y0 + 1, x1 = x0 + 1;
  float my0 = (y0 >= 0 && y0 < H) ? 1.f : 0.f;
  float my1 = (y1 >= 0 && y1 < H) ? 1.f : 0.f;
  float mx0 = (x0 >= 0 && x0 < W) ? 1.f : 0.f;
  float mx1 = (x1 >= 0 && x1 < W) ? 1.f : 0.f;
  int y0c = min(max(y0, 0), H - 1), y1c = min(max(y1, 0), H - 1);
  int x0c = min(max(x0, 0), W - 1), x1c = min(max(x1, 0), W - 1);
  uint32_t packed = (uint32_t)y0c | ((uint32_t)y1c << 8) |
                    ((uint32_t)x0c << 16) | ((uint32_t)x1c << 24);
  float wy0m = wy0 * my0, wy1m = wy1 * my1;
  float wx0m = wx0 * mx0, wx1m = wx1 * mx1;
  uint32_t* pp = pre + (size_t)wave * 135 + lane * 5;
  pp[0] = packed;
  pp[1] = __float_as_uint(wy0m * wx0m);
  pp[2] = __float_as_uint(wy0m * wx1m);
  pp[3] = __float_as_uint(wy1m * wx0m);
  pp[4] = __float_as_uint(wy1m * wx1m);
}

// ---------------------------------------------------------------------------
// Kernel 4: deform_sum. One wave per pixel, lane = channel. Weights preloaded
// coalesced from transposed layout; coordinates via scalar (s_load) pre reads.
// ---------------------------------------------------------------------------
__global__ __launch_bounds__(256) void k_deform(const float* __restrict__ xt,
                                                const uint32_t* __restrict__ pre,
                                                const float* __restrict__ wdeft,
                                                float* __restrict__ dsum) {
  int wave = (swz(blockIdx.x, P / 4) * 256 + (int)threadIdx.x) >> 6;  // P waves
  int c = threadIdx.x & 63;
  int spix = __builtin_amdgcn_readfirstlane(wave);
  int b = spix / HW;
  const float* xb = xt + (size_t)b * HW * 64 + c;
  const uint32_t* pp = pre + (size_t)spix * 135;

  float wd[27];
  #pragma unroll
  for (int i = 0; i < 27; ++i) wd[i] = wdeft[i * 64 + c];   // coalesced

  float acc = 0.f;
  #pragma unroll
  for (int di = 0; di < 3; ++di) {
    #pragma unroll
    for (int k = 0; k < 9; ++k) {
      const uint32_t* ps = pp + (di * 9 + k) * 5;
      uint32_t pk = ps[0];
      float w00 = __uint_as_float(ps[1]);
      float w01 = __uint_as_float(ps[2]);
      float w10 = __uint_as_float(ps[3]);
      float w11 = __uint_as_float(ps[4]);
      int y0 = pk & 255, y1 = (pk >> 8) & 255;
      int x0 = (pk >> 16) & 255, x1 = pk >> 24;
      int r0 = y0 * W, r1 = y1 * W;
      float v00 = xb[(size_t)(r0 + x0) * 64];
      float v01 = xb[(size_t)(r0 + x1) * 64];
      float v10 = xb[(size_t)(r1 + x0) * 64];
      float v11 = xb[(size_t)(r1 + x1) * 64];
      float bil = fmaf(v11, w11, fmaf(v10, w10, fmaf(v01, w01, v00 * w00)));
      acc = fmaf(wd[di * 9 + k], bil, acc);
    }
  }
  dsum[(size_t)wave * 64 + c] = acc;
}

// ---------------------------------------------------------------------------
// Kernel 5: out = bn(1x1 conv 64->64) * x    (NHWC in, NCHW out)
// ---------------------------------------------------------------------------
__global__ __launch_bounds__(256) void k_final(const float* __restrict__ ds,
    const float* __restrict__ x, const float* __restrict__ wb,
    const float* __restrict__ bb, const float* __restrict__ bnb,
    float* __restrict__ out) {
  int blk = swz(blockIdx.x, P / 64);
  int w0 = (blk % (W / 64)) * 64;
  int h  = (blk / (W / 64)) % H;
  int b  = blk / ((W / 64) * H);
  __shared__ float dtile[64][68];       // [pixel][channel], padded for b128
  __shared__ float scs[64], shb[64];    // BN scale / (bias*sc + shift)
  int tx = threadIdx.x & 63;
  int ty = threadIdx.x >> 6;
  int pixbase = (b * H + h) * W + w0;

  {
    int pr  = threadIdx.x >> 4;          // 0..15
    int ic4 = (threadIdx.x & 15) * 4;    // channel quad
    #pragma unroll
    for (int pass = 0; pass < 4; ++pass) {
      int pix = pass * 16 + pr;
      float4 v = *(const float4*)&ds[(size_t)(pixbase + pix) * 64 + ic4];
      *(float4*)&dtile[pix][ic4] = v;
    }
  }
  if (threadIdx.x < 64) {
    float g = bnb[threadIdx.x], vv = bnb[192 + threadIdx.x];
    float sc = g / sqrtf(vv + EPS);
    scs[threadIdx.x] = sc;
    shb[threadIdx.x] = fmaf(bb[threadIdx.x], sc,
                            bnb[64 + threadIdx.x] - bnb[128 + threadIdx.x] * sc);
  }
  __syncthreads();

  float dreg[64];
  #pragma unroll
  for (int q = 0; q < 16; ++q) {
    float4 v = *(float4*)&dtile[tx][q * 4];
    dreg[4 * q + 0] = v.x; dreg[4 * q + 1] = v.y;
    dreg[4 * q + 2] = v.z; dreg[4 * q + 3] = v.w;
  }

  int ocb = __builtin_amdgcn_readfirstlane(ty);   // force SGPR weight loads
  #pragma unroll
  for (int j = 0; j < 16; ++j) {
    int oc = ocb + 4 * j;
    const float* wr = wb + oc * 64;
    float a0 = 0.f, a1 = 0.f, a2 = 0.f, a3 = 0.f;
    #pragma unroll
    for (int q = 0; q < 16; ++q) {
      a0 = fmaf(dreg[4 * q + 0], wr[4 * q + 0], a0);
      a1 = fmaf(dreg[4 * q + 1], wr[4 * q + 1], a1);
      a2 = fmaf(dreg[4 * q + 2], wr[4 * q + 2], a2);
      a3 = fmaf(dreg[4 * q + 3], wr[4 * q + 3], a3);
    }
    float s = (a0 + a1) + (a2 + a3);
    float val = fmaf(s, scs[oc], shb[oc]);
    int xi = ((b * C + oc) * H + h) * W + w0 + tx;
    out[xi] = val * x[xi];
  }
}

// ---------------------------------------------------------------------------
extern "C" void kernel_launch(void* const* d_in, const int* in_sizes, int n_in,
                              void* d_out, int out_size, void* d_ws, size_t ws_size,
                              hipStream_t stream) {
  const float* x     = (const float*)d_in[0];
  const float* w1    = (const float*)d_in[1];
  const float* b1    = (const float*)d_in[2];
  const float* bn1   = (const float*)d_in[3];
  const float* w2    = (const float*)d_in[4];
  const float* b2    = (const float*)d_in[5];
  const float* bn2   = (const float*)d_in[6];
  const float* w3    = (const float*)d_in[7];
  const float* b3    = (const float*)d_in[8];
  const float* bn3   = (const float*)d_in[9];
  const float* wbo   = (const float*)d_in[10];
  const float* bbo   = (const float*)d_in[11];
  const float* bnbo  = (const float*)d_in[12];
  const float* wdef  = (const float*)d_in[13];
  const float* wbal  = (const float*)d_in[14];
  const float* bbal  = (const float*)d_in[15];
  const float* bnbal = (const float*)d_in[16];
  float* out = (float*)d_out;

  float*    xt      = (float*)d_ws;                      // P*64 f
  float*    off_sum = xt + (size_t)P * 64;               // P*64 f
  float*    offs    = off_sum + (size_t)P * 64;          // P*18 f
  uint32_t* pre     = (uint32_t*)(offs + (size_t)P * 18);// P*135 u32 (39.8 MB)
  float*    wts     = (float*)(pre + (size_t)P * 135);   // 4224 f
  float*    w1t     = wts;                               // [15][64]
  float*    w2t     = wts + 960;                         // [15][64]
  float*    w3t     = wts + 1920;                        // [9][64]
  float*    wdeft   = wts + 2496;                        // [27][64]
  float*    dsum    = off_sum;                           // reuse after k_offsets

  k_prepw<<<1, 256, 0, stream>>>(w1, w2, w3, wdef, w1t, w2t, w3t, wdeft);
  k_transpose<<<B * H * (W / 64), 256, 0, stream>>>(x, xt);
  k_offsum<<<P / 16, 256, 0, stream>>>(xt, w1t, b1, bn1, w2t, b2, bn2, w3t, b3, bn3, off_sum);
  k_offsets<<<(P * 18) / 256, 256, 0, stream>>>(off_sum, wbo, bbo, bnbo, offs);
  k_precomp<<<P / 4, 256, 0, stream>>>(offs, pre);
  k_deform<<<P / 4, 256, 0, stream>>>(xt, pre, wdeft, dsum);
  k_final<<<P / 64, 256, 0, stream>>>(dsum, x, wbal, bbal, bnbal, out);
}

// Round 7
// 291.230 us; speedup vs baseline: 2.4814x; 1.0001x over previous
//
#include <hip/hip_runtime.h>
#include <stdint.h>

constexpr int B = 2, C = 64, H = 192, W = 192;
constexpr int HW = H * W;
constexpr int P = B * H * W;          // 73728 pixels
constexpr float EPS = 1e-5f;

// XCD-aware bijective block swizzle (all grids divisible by 8). Chunks of ALL
// kernels cover the same contiguous pixel regions -> cross-kernel L2 reuse.
__device__ __forceinline__ int swz(int bid, int nwg) {
  return (bid & 7) * (nwg >> 3) + (bid >> 3);
}

// ---------------------------------------------------------------------------
// Kernel 0: transpose weight tensors to channel-contiguous [tap][c] layouts.
// 8 blocks (was 1 -> serialized on one CU).
// ---------------------------------------------------------------------------
__global__ __launch_bounds__(256) void k_prepw(const float* __restrict__ w1,
    const float* __restrict__ w2, const float* __restrict__ w3,
    const float* __restrict__ wdef, float* __restrict__ w1t,
    float* __restrict__ w2t, float* __restrict__ w3t, float* __restrict__ wdeft) {
  int gid = blockIdx.x * 256 + threadIdx.x;
  const int stride = 8 * 256;
  for (int i = gid; i < 960; i += stride) {   // [15][64]
    int c = i & 63, j = i >> 6;
    w1t[i] = w1[c * 15 + j];
    w2t[i] = w2[c * 15 + j];
  }
  for (int i = gid; i < 576; i += stride) {   // [9][64]
    int c = i & 63, j = i >> 6;
    w3t[i] = w3[c * 9 + j];
  }
  for (int i = gid; i < 1728; i += stride) {  // [27][64] (di*9+k major)
    int c = i & 63, jk = i >> 6;
    int di = jk / 9, k = jk % 9;
    wdeft[i] = wdef[di * (C * 9) + c * 9 + k];
  }
}

// ---------------------------------------------------------------------------
// Kernel 1: NCHW -> NHWC transpose of x
// ---------------------------------------------------------------------------
__global__ __launch_bounds__(256) void k_transpose(const float* __restrict__ x,
                                                   float* __restrict__ xt) {
  int blk = swz(blockIdx.x, B * H * (W / 64));
  int wt  = blk % (W / 64);
  int h   = (blk / (W / 64)) % H;
  int b   = blk / ((W / 64) * H);
  int w0  = wt * 64;
  __shared__ float tile[64][65];
  int tx = threadIdx.x & 63;
  int ty = threadIdx.x >> 6;
  #pragma unroll
  for (int c = ty; c < 64; c += 4)
    tile[c][tx] = x[((b * C + c) * H + h) * W + w0 + tx];
  __syncthreads();
  #pragma unroll
  for (int wi = ty; wi < 64; wi += 4)
    xt[((b * H + h) * W + w0 + wi) * 64 + tx] = tile[tx][wi];
}

// ---------------------------------------------------------------------------
// Kernel 2: off_sum = bn1(dw1x15) + bn2(dw15x1) + bn3(dw3x3)   (NHWC in/out)
// ---------------------------------------------------------------------------
__global__ __launch_bounds__(256) void k_offsum(const float* __restrict__ xt,
    const float* __restrict__ w1t, const float* __restrict__ b1, const float* __restrict__ bn1,
    const float* __restrict__ w2t, const float* __restrict__ b2, const float* __restrict__ bn2,
    const float* __restrict__ w3t, const float* __restrict__ b3, const float* __restrict__ bn3,
    float* __restrict__ out) {
  int wave = (swz(blockIdx.x, P / 16) * 256 + (int)threadIdx.x) >> 6;  // P/4 waves
  int c = threadIdx.x & 63;
  int w0 = (wave % (W / 4)) * 4;
  int h  = (wave / (W / 4)) % H;
  int b  = wave / ((W / 4) * H);
  const float* xb = xt + (size_t)b * HW * 64 + c;

  float s1[4] = {0.f, 0.f, 0.f, 0.f};
  float s2[4] = {0.f, 0.f, 0.f, 0.f};
  float s3[4] = {0.f, 0.f, 0.f, 0.f};

  {
    float xv[18];
    #pragma unroll
    for (int j = 0; j < 18; ++j) {
      int ww = w0 - 7 + j;
      xv[j] = (ww >= 0 && ww < W) ? xb[(h * W + ww) * 64] : 0.f;
    }
    #pragma unroll
    for (int j = 0; j < 15; ++j) {
      float wj = w1t[j * 64 + c];
      #pragma unroll
      for (int p = 0; p < 4; ++p) s1[p] = fmaf(xv[p + j], wj, s1[p]);
    }
  }
  #pragma unroll
  for (int j = 0; j < 15; ++j) {
    int hh = h - 7 + j;
    if (hh >= 0 && hh < H) {
      float wj = w2t[j * 64 + c];
      #pragma unroll
      for (int p = 0; p < 4; ++p)
        s2[p] = fmaf(xb[(hh * W + w0 + p) * 64], wj, s2[p]);
    }
  }
  #pragma unroll
  for (int dy = -1; dy <= 1; ++dy) {
    int hh = h + dy;
    if (hh < 0 || hh >= H) continue;
    float rv[6];
    #pragma unroll
    for (int j = 0; j < 6; ++j) {
      int ww = w0 - 1 + j;
      rv[j] = (ww >= 0 && ww < W) ? xb[(hh * W + ww) * 64] : 0.f;
    }
    #pragma unroll
    for (int dx = 0; dx < 3; ++dx) {
      float wj = w3t[((dy + 1) * 3 + dx) * 64 + c];
      #pragma unroll
      for (int p = 0; p < 4; ++p) s3[p] = fmaf(rv[p + dx], wj, s3[p]);
    }
  }

  float sc1 = bn1[c] / sqrtf(bn1[192 + c] + EPS);
  float sh1 = bn1[64 + c] - bn1[128 + c] * sc1;
  float sc2 = bn2[c] / sqrtf(bn2[192 + c] + EPS);
  float sh2 = bn2[64 + c] - bn2[128 + c] * sc2;
  float sc3 = bn3[c] / sqrtf(bn3[192 + c] + EPS);
  float sh3 = bn3[64 + c] - bn3[128 + c] * sc3;
  float bb1 = b1[c], bb2 = b2[c], bb3 = b3[c];
  #pragma unroll
  for (int p = 0; p < 4; ++p)
    out[((size_t)wave * 4 + p) * 64 + c] =
        fmaf(s1[p] + bb1, sc1, sh1) + fmaf(s2[p] + bb2, sc2, sh2) +
        fmaf(s3[p] + bb3, sc3, sh3);
}

// ---------------------------------------------------------------------------
// Kernel 3: offsets = bn(1x1 conv 64->18)   (NHWC: out[pix*18 + o])
// ---------------------------------------------------------------------------
__global__ __launch_bounds__(256) void k_offsets(const float* __restrict__ off_sum,
    const float* __restrict__ wq, const float* __restrict__ bq,
    const float* __restrict__ bnq, float* __restrict__ out) {
  int idx = swz(blockIdx.x, (P * 18) / 256) * 256 + (int)threadIdx.x;
  int o   = idx % 18;
  int pix = idx / 18;
  const float4* v  = (const float4*)(off_sum + (size_t)pix * 64);
  const float4* wv = (const float4*)(wq + o * 64);
  float s = 0.f;
  #pragma unroll
  for (int j = 0; j < 16; ++j) {
    float4 a = v[j], ww = wv[j];
    s = fmaf(a.x, ww.x, s); s = fmaf(a.y, ww.y, s);
    s = fmaf(a.z, ww.z, s); s = fmaf(a.w, ww.w, s);
  }
  float sc = bnq[o] / sqrtf(bnq[54 + o] + EPS);
  float sh = bnq[18 + o] - bnq[36 + o] * sc;
  out[idx] = fmaf(s + bq[o], sc, sh);
}

// ---------------------------------------------------------------------------
// Kernel 4: FUSED precomp + deform_sum. One wave per pixel, lane = channel.
// Phase 1 (lanes 0..26 = dil*9+tap): exact old-k_precomp coordinate math,
// results to per-wave LDS (8 dwords/tap: [pk,w00,w01,w10][w11,...], 16B
// aligned so phase 2 reads 1x ds_read_b128 + 1x ds_read_b32, uniform addr =
// broadcast). Kills the 39.8 MB pre table (HBM round-trip + scalar-load
// stalls: FETCH_SIZE was 49.75 MB) and the separate k_precomp launch.
// ---------------------------------------------------------------------------
__global__ __launch_bounds__(256) void k_deform(const float* __restrict__ xt,
                                                const float* __restrict__ offs,
                                                const float* __restrict__ wdeft,
                                                float* __restrict__ dsum) {
  __shared__ uint32_t lpre[4][27 * 8 + 4];   // per-wave region, +4 pad
  int wl   = threadIdx.x >> 6;               // wave within block
  int lane = threadIdx.x & 63;
  int pix  = swz(blockIdx.x, P / 4) * 4 + wl;

  // ---- phase 1: per-tap coordinate precompute (27 lanes) ----
  if (lane < 27) {
    int di = lane / 9, k = lane % 9;
    int d  = 1 << di;                       // 1,2,4
    int w = pix % W, h = (pix / W) % H;
    float offy = offs[(size_t)pix * 18 + 2 * k];
    float offx = offs[(size_t)pix * 18 + 2 * k + 1];
    int ky = k / 3 - 1, kx = k % 3 - 1;
    float yy = (offy + (float)h) + (float)(ky * d);
    float xx = (offx + (float)w) + (float)(kx * d);
    float y0f = floorf(yy), x0f = floorf(xx);
    float wy1 = yy - y0f, wx1 = xx - x0f;
    float wy0 = 1.f - wy1, wx0 = 1.f - wx1;
    int y0 = (int)fmaxf(fminf(y0f, 1.0e4f), -1.0e4f);
    int x0 = (int)fmaxf(fminf(x0f, 1.0e4f), -1.0e4f);
    int y1 = y0 + 1, x1 = x0 + 1;
    float my0 = (y0 >= 0 && y0 < H) ? 1.f : 0.f;
    float my1 = (y1 >= 0 && y1 < H) ? 1.f : 0.f;
    float mx0 = (x0 >= 0 && x0 < W) ? 1.f : 0.f;
    float mx1 = (x1 >= 0 && x1 < W) ? 1.f : 0.f;
    int y0c = min(max(y0, 0), H - 1), y1c = min(max(y1, 0), H - 1);
    int x0c = min(max(x0, 0), W - 1), x1c = min(max(x1, 0), W - 1);
    uint32_t packed = (uint32_t)y0c | ((uint32_t)y1c << 8) |
                      ((uint32_t)x0c << 16) | ((uint32_t)x1c << 24);
    float wy0m = wy0 * my0, wy1m = wy1 * my1;
    float wx0m = wx0 * mx0, wx1m = wx1 * mx1;
    uint32_t* q = &lpre[wl][lane * 8];
    q[0] = packed;
    q[1] = __float_as_uint(wy0m * wx0m);
    q[2] = __float_as_uint(wy0m * wx1m);
    q[3] = __float_as_uint(wy1m * wx0m);
    q[4] = __float_as_uint(wy1m * wx1m);
  }
  __syncthreads();

  // ---- phase 2: gathers + accumulate ----
  int c = lane;
  int b = pix / HW;
  const float* xb = xt + (size_t)b * HW * 64 + c;

  float wd[27];
  #pragma unroll
  for (int i = 0; i < 27; ++i) wd[i] = wdeft[i * 64 + c];   // coalesced

  float acc = 0.f;
  #pragma unroll
  for (int t = 0; t < 27; ++t) {
    uint4 m = *(const uint4*)&lpre[wl][t * 8];     // ds_read_b128, broadcast
    float w11 = __uint_as_float(lpre[wl][t * 8 + 4]);
    uint32_t pk = m.x;
    float w00 = __uint_as_float(m.y);
    float w01 = __uint_as_float(m.z);
    float w10 = __uint_as_float(m.w);
    int y0 = pk & 255, y1 = (pk >> 8) & 255;
    int x0 = (pk >> 16) & 255, x1 = pk >> 24;
    int r0 = y0 * W, r1 = y1 * W;
    float v00 = xb[(size_t)(r0 + x0) * 64];
    float v01 = xb[(size_t)(r0 + x1) * 64];
    float v10 = xb[(size_t)(r1 + x0) * 64];
    float v11 = xb[(size_t)(r1 + x1) * 64];
    float bil = fmaf(v11, w11, fmaf(v10, w10, fmaf(v01, w01, v00 * w00)));
    acc = fmaf(wd[t], bil, acc);
  }
  dsum[(size_t)pix * 64 + c] = acc;
}

// ---------------------------------------------------------------------------
// Kernel 5: out = bn(1x1 conv 64->64) * x    (NHWC in, NCHW out)
// ---------------------------------------------------------------------------
__global__ __launch_bounds__(256) void k_final(const float* __restrict__ ds,
    const float* __restrict__ x, const float* __restrict__ wb,
    const float* __restrict__ bb, const float* __restrict__ bnb,
    float* __restrict__ out) {
  int blk = swz(blockIdx.x, P / 64);
  int w0 = (blk % (W / 64)) * 64;
  int h  = (blk / (W / 64)) % H;
  int b  = blk / ((W / 64) * H);
  __shared__ float dtile[64][68];       // [pixel][channel], padded for b128
  __shared__ float scs[64], shb[64];    // BN scale / (bias*sc + shift)
  int tx = threadIdx.x & 63;
  int ty = threadIdx.x >> 6;
  int pixbase = (b * H + h) * W + w0;

  {
    int pr  = threadIdx.x >> 4;          // 0..15
    int ic4 = (threadIdx.x & 15) * 4;    // channel quad
    #pragma unroll
    for (int pass = 0; pass < 4; ++pass) {
      int pix = pass * 16 + pr;
      float4 v = *(const float4*)&ds[(size_t)(pixbase + pix) * 64 + ic4];
      *(float4*)&dtile[pix][ic4] = v;
    }
  }
  if (threadIdx.x < 64) {
    float g = bnb[threadIdx.x], vv = bnb[192 + threadIdx.x];
    float sc = g / sqrtf(vv + EPS);
    scs[threadIdx.x] = sc;
    shb[threadIdx.x] = fmaf(bb[threadIdx.x], sc,
                            bnb[64 + threadIdx.x] - bnb[128 + threadIdx.x] * sc);
  }
  __syncthreads();

  float dreg[64];
  #pragma unroll
  for (int q = 0; q < 16; ++q) {
    float4 v = *(float4*)&dtile[tx][q * 4];
    dreg[4 * q + 0] = v.x; dreg[4 * q + 1] = v.y;
    dreg[4 * q + 2] = v.z; dreg[4 * q + 3] = v.w;
  }

  int ocb = __builtin_amdgcn_readfirstlane(ty);   // force SGPR weight loads
  #pragma unroll
  for (int j = 0; j < 16; ++j) {
    int oc = ocb + 4 * j;
    const float* wr = wb + oc * 64;
    float a0 = 0.f, a1 = 0.f, a2 = 0.f, a3 = 0.f;
    #pragma unroll
    for (int q = 0; q < 16; ++q) {
      a0 = fmaf(dreg[4 * q + 0], wr[4 * q + 0], a0);
      a1 = fmaf(dreg[4 * q + 1], wr[4 * q + 1], a1);
      a2 = fmaf(dreg[4 * q + 2], wr[4 * q + 2], a2);
      a3 = fmaf(dreg[4 * q + 3], wr[4 * q + 3], a3);
    }
    float s = (a0 + a1) + (a2 + a3);
    float val = fmaf(s, scs[oc], shb[oc]);
    int xi = ((b * C + oc) * H + h) * W + w0 + tx;
    out[xi] = val * x[xi];
  }
}

// ---------------------------------------------------------------------------
extern "C" void kernel_launch(void* const* d_in, const int* in_sizes, int n_in,
                              void* d_out, int out_size, void* d_ws, size_t ws_size,
                              hipStream_t stream) {
  const float* x     = (const float*)d_in[0];
  const float* w1    = (const float*)d_in[1];
  const float* b1    = (const float*)d_in[2];
  const float* bn1   = (const float*)d_in[3];
  const float* w2    = (const float*)d_in[4];
  const float* b2    = (const float*)d_in[5];
  const float* bn2   = (const float*)d_in[6];
  const float* w3    = (const float*)d_in[7];
  const float* b3    = (const float*)d_in[8];
  const float* bn3   = (const float*)d_in[9];
  const float* wbo   = (const float*)d_in[10];
  const float* bbo   = (const float*)d_in[11];
  const float* bnbo  = (const float*)d_in[12];
  const float* wdef  = (const float*)d_in[13];
  const float* wbal  = (const float*)d_in[14];
  const float* bbal  = (const float*)d_in[15];
  const float* bnbal = (const float*)d_in[16];
  float* out = (float*)d_out;

  float*    xt      = (float*)d_ws;                      // P*64 f
  float*    off_sum = xt + (size_t)P * 64;               // P*64 f
  float*    offs    = off_sum + (size_t)P * 64;          // P*18 f
  float*    wts     = offs + (size_t)P * 18;             // 4224 f
  float*    w1t     = wts;                               // [15][64]
  float*    w2t     = wts + 960;                         // [15][64]
  float*    w3t     = wts + 1920;                        // [9][64]
  float*    wdeft   = wts + 2496;                        // [27][64]
  float*    dsum    = off_sum;                           // reuse after k_offsets

  k_prepw<<<8, 256, 0, stream>>>(w1, w2, w3, wdef, w1t, w2t, w3t, wdeft);
  k_transpose<<<B * H * (W / 64), 256, 0, stream>>>(x, xt);
  k_offsum<<<P / 16, 256, 0, stream>>>(xt, w1t, b1, bn1, w2t, b2, bn2, w3t, b3, bn3, off_sum);
  k_offsets<<<(P * 18) / 256, 256, 0, stream>>>(off_sum, wbo, bbo, bnbo, offs);
  k_deform<<<P / 4, 256, 0, stream>>>(xt, offs, wdeft, dsum);
  k_final<<<P / 64, 256, 0, stream>>>(dsum, x, wbal, bbal, bnbal, out);
}

// Round 8
// 244.707 us; speedup vs baseline: 2.9531x; 1.1901x over previous
//
#include <hip/hip_runtime.h>
#include <stdint.h>

constexpr int B = 2, C = 64, H = 192, W = 192;
constexpr int HW = H * W;
constexpr int P = B * H * W;          // 73728 pixels
constexpr float EPS = 1e-5f;

// XCD-aware bijective block swizzle (all grids divisible by 8). Chunks of ALL
// kernels cover the same contiguous pixel regions -> cross-kernel L2 reuse.
__device__ __forceinline__ int swz(int bid, int nwg) {
  return (bid & 7) * (nwg >> 3) + (bid >> 3);
}

// ---------------------------------------------------------------------------
// Kernel 0: transpose weight tensors to channel-contiguous [tap][c] layouts.
// ---------------------------------------------------------------------------
__global__ __launch_bounds__(256) void k_prepw(const float* __restrict__ w1,
    const float* __restrict__ w2, const float* __restrict__ w3,
    const float* __restrict__ wdef, float* __restrict__ w1t,
    float* __restrict__ w2t, float* __restrict__ w3t, float* __restrict__ wdeft) {
  int gid = blockIdx.x * 256 + threadIdx.x;
  const int stride = 8 * 256;
  for (int i = gid; i < 960; i += stride) {   // [15][64]
    int c = i & 63, j = i >> 6;
    w1t[i] = w1[c * 15 + j];
    w2t[i] = w2[c * 15 + j];
  }
  for (int i = gid; i < 576; i += stride) {   // [9][64]
    int c = i & 63, j = i >> 6;
    w3t[i] = w3[c * 9 + j];
  }
  for (int i = gid; i < 1728; i += stride) {  // [27][64] (di*9+k major)
    int c = i & 63, jk = i >> 6;
    int di = jk / 9, k = jk % 9;
    wdeft[i] = wdef[di * (C * 9) + c * 9 + k];
  }
}

// ---------------------------------------------------------------------------
// Kernel 1: NCHW -> NHWC transpose of x
// ---------------------------------------------------------------------------
__global__ __launch_bounds__(256) void k_transpose(const float* __restrict__ x,
                                                   float* __restrict__ xt) {
  int blk = swz(blockIdx.x, B * H * (W / 64));
  int wt  = blk % (W / 64);
  int h   = (blk / (W / 64)) % H;
  int b   = blk / ((W / 64) * H);
  int w0  = wt * 64;
  __shared__ float tile[64][65];
  int tx = threadIdx.x & 63;
  int ty = threadIdx.x >> 6;
  #pragma unroll
  for (int c = ty; c < 64; c += 4)
    tile[c][tx] = x[((b * C + c) * H + h) * W + w0 + tx];
  __syncthreads();
  #pragma unroll
  for (int wi = ty; wi < 64; wi += 4)
    xt[((b * H + h) * W + w0 + wi) * 64 + tx] = tile[tx][wi];
}

// ---------------------------------------------------------------------------
// Kernel 2: FUSED off_sum + offsets.
// Phase A: per wave, off_sum for 4 consecutive-w pixels (lane=channel),
//          results to LDS tile os[16][68] (never touches HBM).
// Phase B: 64->18 matvec per pixel from LDS (wq staged to LDS [18][66]),
//          BN'd, written to offs[pix*18+o] (5.3 MB) only.
// Kills off_sum's 38 MB HBM round-trip + k_offsets' 18x re-read + 1 launch.
// ---------------------------------------------------------------------------
__global__ __launch_bounds__(256) void k_offpipe(const float* __restrict__ xt,
    const float* __restrict__ w1t, const float* __restrict__ b1, const float* __restrict__ bn1,
    const float* __restrict__ w2t, const float* __restrict__ b2, const float* __restrict__ bn2,
    const float* __restrict__ w3t, const float* __restrict__ b3, const float* __restrict__ bn3,
    const float* __restrict__ wq, const float* __restrict__ bq, const float* __restrict__ bnq,
    float* __restrict__ offs) {
  __shared__ float os[16][68];
  __shared__ float wqs[18][66];
  __shared__ float qsc[18], qsh[18];

  int blk = swz(blockIdx.x, P / 16);
  int w0t = (blk % (W / 16)) * 16;
  int h   = (blk / (W / 16)) % H;
  int b   = blk / ((W / 16) * H);
  int wl  = threadIdx.x >> 6;
  int c   = threadIdx.x & 63;
  int w0  = w0t + wl * 4;
  const float* xb = xt + (size_t)b * HW * 64 + c;

  // ---- stage wq + BN(18) ----
  for (int i = threadIdx.x; i < 18 * 64; i += 256)
    wqs[i >> 6][i & 63] = wq[i];
  if (threadIdx.x < 18) {
    int o = threadIdx.x;
    float sc = bnq[o] / sqrtf(bnq[54 + o] + EPS);
    qsc[o] = sc;
    qsh[o] = fmaf(bq[o], sc, bnq[18 + o] - bnq[36 + o] * sc);
  }

  // ---- phase A: off_sum for 4 pixels (verified k_offsum math) ----
  float s1[4] = {0.f, 0.f, 0.f, 0.f};
  float s2[4] = {0.f, 0.f, 0.f, 0.f};
  float s3[4] = {0.f, 0.f, 0.f, 0.f};
  {
    float xv[18];
    #pragma unroll
    for (int j = 0; j < 18; ++j) {
      int ww = w0 - 7 + j;
      xv[j] = (ww >= 0 && ww < W) ? xb[(h * W + ww) * 64] : 0.f;
    }
    #pragma unroll
    for (int j = 0; j < 15; ++j) {
      float wj = w1t[j * 64 + c];
      #pragma unroll
      for (int p = 0; p < 4; ++p) s1[p] = fmaf(xv[p + j], wj, s1[p]);
    }
  }
  #pragma unroll
  for (int j = 0; j < 15; ++j) {
    int hh = h - 7 + j;
    if (hh >= 0 && hh < H) {
      float wj = w2t[j * 64 + c];
      #pragma unroll
      for (int p = 0; p < 4; ++p)
        s2[p] = fmaf(xb[(hh * W + w0 + p) * 64], wj, s2[p]);
    }
  }
  #pragma unroll
  for (int dy = -1; dy <= 1; ++dy) {
    int hh = h + dy;
    if (hh >= 0 && hh < H) {
      float rv[6];
      #pragma unroll
      for (int j = 0; j < 6; ++j) {
        int ww = w0 - 1 + j;
        rv[j] = (ww >= 0 && ww < W) ? xb[(hh * W + ww) * 64] : 0.f;
      }
      #pragma unroll
      for (int dx = 0; dx < 3; ++dx) {
        float wj = w3t[((dy + 1) * 3 + dx) * 64 + c];
        #pragma unroll
        for (int p = 0; p < 4; ++p) s3[p] = fmaf(rv[p + dx], wj, s3[p]);
      }
    }
  }
  float sc1 = bn1[c] / sqrtf(bn1[192 + c] + EPS);
  float sh1 = bn1[64 + c] - bn1[128 + c] * sc1;
  float sc2 = bn2[c] / sqrtf(bn2[192 + c] + EPS);
  float sh2 = bn2[64 + c] - bn2[128 + c] * sc2;
  float sc3 = bn3[c] / sqrtf(bn3[192 + c] + EPS);
  float sh3 = bn3[64 + c] - bn3[128 + c] * sc3;
  float bb1 = b1[c], bb2 = b2[c], bb3 = b3[c];
  #pragma unroll
  for (int p = 0; p < 4; ++p)
    os[wl * 4 + p][c] =
        fmaf(s1[p] + bb1, sc1, sh1) + fmaf(s2[p] + bb2, sc2, sh2) +
        fmaf(s3[p] + bb3, sc3, sh3);
  __syncthreads();

  // ---- phase B: 64->18 matvec per pixel ----
  int p  = threadIdx.x & 15;            // pixel in tile
  int og = threadIdx.x >> 4;            // 0..15
  float dreg[64];
  #pragma unroll
  for (int q = 0; q < 16; ++q) {
    float4 v = *(float4*)&os[p][q * 4];
    dreg[4 * q + 0] = v.x; dreg[4 * q + 1] = v.y;
    dreg[4 * q + 2] = v.z; dreg[4 * q + 3] = v.w;
  }
  size_t pix = (size_t)((b * H + h) * W + w0t + p);
  #pragma unroll
  for (int pass = 0; pass < 2; ++pass) {
    int o = (pass == 0) ? og : 16 + og;
    if (pass == 1 && og >= 2) break;
    float a0 = 0.f, a1 = 0.f, a2 = 0.f, a3 = 0.f;
    #pragma unroll
    for (int q = 0; q < 16; ++q) {
      float4 ww = *(float4*)&wqs[o][q * 4];
      a0 = fmaf(dreg[4 * q + 0], ww.x, a0);
      a1 = fmaf(dreg[4 * q + 1], ww.y, a1);
      a2 = fmaf(dreg[4 * q + 2], ww.z, a2);
      a3 = fmaf(dreg[4 * q + 3], ww.w, a3);
    }
    float s = (a0 + a1) + (a2 + a3);
    offs[pix * 18 + o] = fmaf(s, qsc[o], qsh[o]);
  }
}

// ---------------------------------------------------------------------------
// Kernel 4: FUSED precomp + deform_sum. One wave per pixel, lane = channel.
// Phase 1 (lanes 0..26): coordinate math -> LDS stores 4 BYTE OFFSETS +
// 4 weights (8 dwords/tap). Phase 2 per tap: 2x ds_read_b128 + 4x
// readfirstlane (corner offsets -> SGPR base, so gathers are
// global_load v,c4,s[base] with SALU address adds) + 5 FMA.
// r7 had ~25 VALU slots/tap (unpack + y*W + 64b addr adds all on VALU,
// VALUBusy 80.5%); this cuts to ~11.
// ---------------------------------------------------------------------------
__global__ __launch_bounds__(256) void k_deform(const float* __restrict__ xt,
                                                const float* __restrict__ offs,
                                                const float* __restrict__ wdeft,
                                                float* __restrict__ dsum) {
  __shared__ uint32_t lpre[4][27 * 8 + 4];
  int wl   = threadIdx.x >> 6;
  int lane = threadIdx.x & 63;
  int pix  = swz(blockIdx.x, P / 4) * 4 + wl;

  // ---- phase 1: per-tap coordinate precompute (27 lanes) ----
  if (lane < 27) {
    int di = lane / 9, k = lane % 9;
    int d  = 1 << di;                       // 1,2,4
    int w = pix % W, h = (pix / W) % H;
    float offy = offs[(size_t)pix * 18 + 2 * k];
    float offx = offs[(size_t)pix * 18 + 2 * k + 1];
    int ky = k / 3 - 1, kx = k % 3 - 1;
    float yy = (offy + (float)h) + (float)(ky * d);
    float xx = (offx + (float)w) + (float)(kx * d);
    float y0f = floorf(yy), x0f = floorf(xx);
    float wy1 = yy - y0f, wx1 = xx - x0f;
    float wy0 = 1.f - wy1, wx0 = 1.f - wx1;
    int y0 = (int)fmaxf(fminf(y0f, 1.0e4f), -1.0e4f);
    int x0 = (int)fmaxf(fminf(x0f, 1.0e4f), -1.0e4f);
    int y1 = y0 + 1, x1 = x0 + 1;
    float my0 = (y0 >= 0 && y0 < H) ? 1.f : 0.f;
    float my1 = (y1 >= 0 && y1 < H) ? 1.f : 0.f;
    float mx0 = (x0 >= 0 && x0 < W) ? 1.f : 0.f;
    float mx1 = (x1 >= 0 && x1 < W) ? 1.f : 0.f;
    int y0c = min(max(y0, 0), H - 1), y1c = min(max(y1, 0), H - 1);
    int x0c = min(max(x0, 0), W - 1), x1c = min(max(x1, 0), W - 1);
    int r0 = y0c * W, r1 = y1c * W;
    float wy0m = wy0 * my0, wy1m = wy1 * my1;
    float wx0m = wx0 * mx0, wx1m = wx1 * mx1;
    uint32_t* q = &lpre[wl][lane * 8];
    q[0] = (uint32_t)(r0 + x0c) << 8;       // byte offsets (x256)
    q[1] = (uint32_t)(r0 + x1c) << 8;
    q[2] = (uint32_t)(r1 + x0c) << 8;
    q[3] = (uint32_t)(r1 + x1c) << 8;
    q[4] = __float_as_uint(wy0m * wx0m);
    q[5] = __float_as_uint(wy0m * wx1m);
    q[6] = __float_as_uint(wy1m * wx0m);
    q[7] = __float_as_uint(wy1m * wx1m);
  }
  __syncthreads();

  // ---- phase 2: gathers + accumulate ----
  int c = lane;
  int b = pix / HW;
  const char* xb0 = (const char*)(xt + (size_t)b * HW * 64);

  float wd[27];
  #pragma unroll
  for (int i = 0; i < 27; ++i) wd[i] = wdeft[i * 64 + c];   // coalesced

  float acc = 0.f;
  #pragma unroll
  for (int t = 0; t < 27; ++t) {
    uint4 ov = *(const uint4*)&lpre[wl][t * 8];
    uint4 wv = *(const uint4*)&lpre[wl][t * 8 + 4];
    int s00 = __builtin_amdgcn_readfirstlane((int)ov.x);
    int s01 = __builtin_amdgcn_readfirstlane((int)ov.y);
    int s10 = __builtin_amdgcn_readfirstlane((int)ov.z);
    int s11 = __builtin_amdgcn_readfirstlane((int)ov.w);
    const float* p00 = (const float*)(xb0 + s00);
    const float* p01 = (const float*)(xb0 + s01);
    const float* p10 = (const float*)(xb0 + s10);
    const float* p11 = (const float*)(xb0 + s11);
    float v00 = p00[c], v01 = p01[c], v10 = p10[c], v11 = p11[c];
    float bil = fmaf(v11, __uint_as_float(wv.w),
                 fmaf(v10, __uint_as_float(wv.z),
                  fmaf(v01, __uint_as_float(wv.y),
                       v00 * __uint_as_float(wv.x))));
    acc = fmaf(wd[t], bil, acc);
  }
  dsum[(size_t)pix * 64 + c] = acc;
}

// ---------------------------------------------------------------------------
// Kernel 5: out = bn(1x1 conv 64->64) * x    (NHWC in, NCHW out)
// ---------------------------------------------------------------------------
__global__ __launch_bounds__(256) void k_final(const float* __restrict__ ds,
    const float* __restrict__ x, const float* __restrict__ wb,
    const float* __restrict__ bb, const float* __restrict__ bnb,
    float* __restrict__ out) {
  int blk = swz(blockIdx.x, P / 64);
  int w0 = (blk % (W / 64)) * 64;
  int h  = (blk / (W / 64)) % H;
  int b  = blk / ((W / 64) * H);
  __shared__ float dtile[64][68];
  __shared__ float scs[64], shb[64];
  int tx = threadIdx.x & 63;
  int ty = threadIdx.x >> 6;
  int pixbase = (b * H + h) * W + w0;

  {
    int pr  = threadIdx.x >> 4;
    int ic4 = (threadIdx.x & 15) * 4;
    #pragma unroll
    for (int pass = 0; pass < 4; ++pass) {
      int pix = pass * 16 + pr;
      float4 v = *(const float4*)&ds[(size_t)(pixbase + pix) * 64 + ic4];
      *(float4*)&dtile[pix][ic4] = v;
    }
  }
  if (threadIdx.x < 64) {
    float g = bnb[threadIdx.x], vv = bnb[192 + threadIdx.x];
    float sc = g / sqrtf(vv + EPS);
    scs[threadIdx.x] = sc;
    shb[threadIdx.x] = fmaf(bb[threadIdx.x], sc,
                            bnb[64 + threadIdx.x] - bnb[128 + threadIdx.x] * sc);
  }
  __syncthreads();

  float dreg[64];
  #pragma unroll
  for (int q = 0; q < 16; ++q) {
    float4 v = *(float4*)&dtile[tx][q * 4];
    dreg[4 * q + 0] = v.x; dreg[4 * q + 1] = v.y;
    dreg[4 * q + 2] = v.z; dreg[4 * q + 3] = v.w;
  }

  int ocb = __builtin_amdgcn_readfirstlane(ty);
  #pragma unroll
  for (int j = 0; j < 16; ++j) {
    int oc = ocb + 4 * j;
    const float* wr = wb + oc * 64;
    float a0 = 0.f, a1 = 0.f, a2 = 0.f, a3 = 0.f;
    #pragma unroll
    for (int q = 0; q < 16; ++q) {
      a0 = fmaf(dreg[4 * q + 0], wr[4 * q + 0], a0);
      a1 = fmaf(dreg[4 * q + 1], wr[4 * q + 1], a1);
      a2 = fmaf(dreg[4 * q + 2], wr[4 * q + 2], a2);
      a3 = fmaf(dreg[4 * q + 3], wr[4 * q + 3], a3);
    }
    float s = (a0 + a1) + (a2 + a3);
    float val = fmaf(s, scs[oc], shb[oc]);
    int xi = ((b * C + oc) * H + h) * W + w0 + tx;
    out[xi] = val * x[xi];
  }
}

// ---------------------------------------------------------------------------
extern "C" void kernel_launch(void* const* d_in, const int* in_sizes, int n_in,
                              void* d_out, int out_size, void* d_ws, size_t ws_size,
                              hipStream_t stream) {
  const float* x     = (const float*)d_in[0];
  const float* w1    = (const float*)d_in[1];
  const float* b1    = (const float*)d_in[2];
  const float* bn1   = (const float*)d_in[3];
  const float* w2    = (const float*)d_in[4];
  const float* b2    = (const float*)d_in[5];
  const float* bn2   = (const float*)d_in[6];
  const float* w3    = (const float*)d_in[7];
  const float* b3    = (const float*)d_in[8];
  const float* bn3   = (const float*)d_in[9];
  const float* wbo   = (const float*)d_in[10];
  const float* bbo   = (const float*)d_in[11];
  const float* bnbo  = (const float*)d_in[12];
  const float* wdef  = (const float*)d_in[13];
  const float* wbal  = (const float*)d_in[14];
  const float* bbal  = (const float*)d_in[15];
  const float* bnbal = (const float*)d_in[16];
  float* out = (float*)d_out;

  float* xt    = (float*)d_ws;                  // P*64 f
  float* dsum  = xt + (size_t)P * 64;           // P*64 f
  float* offs  = dsum + (size_t)P * 64;         // P*18 f
  float* wts   = offs + (size_t)P * 18;         // 4224 f
  float* w1t   = wts;                           // [15][64]
  float* w2t   = wts + 960;                     // [15][64]
  float* w3t   = wts + 1920;                    // [9][64]
  float* wdeft = wts + 2496;                    // [27][64]

  k_prepw<<<8, 256, 0, stream>>>(w1, w2, w3, wdef, w1t, w2t, w3t, wdeft);
  k_transpose<<<B * H * (W / 64), 256, 0, stream>>>(x, xt);
  k_offpipe<<<P / 16, 256, 0, stream>>>(xt, w1t, b1, bn1, w2t, b2, bn2,
                                        w3t, b3, bn3, wbo, bbo, bnbo, offs);
  k_deform<<<P / 4, 256, 0, stream>>>(xt, offs, wdeft, dsum);
  k_final<<<P / 64, 256, 0, stream>>>(dsum, x, wbal, bbal, bnbal, out);
}